// Round 10
// baseline (685.600 us; speedup 1.0000x reference)
//
#include <hip/hip_runtime.h>

typedef __attribute__((ext_vector_type(8))) short short8;
typedef __attribute__((ext_vector_type(4))) float f32x4;
typedef unsigned short u16;

#define BB   128
#define SS   256
#define FIN  40
#define HH   64
#define DD   128
#define NHH  4
#define LL   2
#define NEGV (-1e9f)

__device__ __forceinline__ u16 f2b(float f) {
    unsigned u = __float_as_uint(f);
    return (u16)((u + 0x7FFFu + ((u >> 16) & 1u)) >> 16);
}
__device__ __forceinline__ float b2f(u16 u) {
    return __uint_as_float(((unsigned)u) << 16);
}

// ---------------------------------------------------------------- merged fp32 -> bf16 weight convert
__global__ __launch_bounds__(256) void cvt_all_kernel(const float* __restrict__ dm_w,
                                                      const float* __restrict__ ip_w,
                                                      const float* __restrict__ op_w,
                                                      const float* __restrict__ l1_w,
                                                      const float* __restrict__ l2_w,
                                                      u16* __restrict__ o_dm, u16* __restrict__ o_ip,
                                                      u16* __restrict__ o_op, u16* __restrict__ o_l1,
                                                      u16* __restrict__ o_l2) {
    int blk = blockIdx.x;
    const float* s; u16* d; int off;
    if      (blk < 4)   { s = dm_w; d = o_dm; off = blk; }
    else if (blk < 52)  { s = ip_w; d = o_ip; off = blk - 4; }
    else if (blk < 68)  { s = op_w; d = o_op; off = blk - 52; }
    else if (blk < 324) { s = l1_w; d = o_l1; off = blk - 68; }
    else                { s = l2_w; d = o_l2; off = blk - 324; }
    int i = (off * 256 + threadIdx.x) * 8;
    float4 a = *(const float4*)&s[i];
    float4 b = *(const float4*)&s[i + 4];
    short8 o;
    o[0] = (short)f2b(a.x); o[1] = (short)f2b(a.y); o[2] = (short)f2b(a.z); o[3] = (short)f2b(a.w);
    o[4] = (short)f2b(b.x); o[5] = (short)f2b(b.y); o[6] = (short)f2b(b.z); o[7] = (short)f2b(b.w);
    *(short8*)&d[i] = o;
}

// ---------------------------------------------------------------- time mask
__global__ __launch_bounds__(256) void tm_kernel(const float* __restrict__ mask,
                                                 float* __restrict__ tm) {
    int i = blockIdx.x * blockDim.x + threadIdx.x;
    if (i >= BB * SS) return;
    const float* m = mask + (size_t)i * FIN;
    float s = 0.f;
    for (int f = 0; f < FIN; ++f) s += m[f];
    tm[i] = (s > 0.f) ? 1.f : 0.f;
}

// ------------------------------------------------- xwt = concat(x,mask,delta) @ W_ih^T + b_ih
// TRANSPOSED output layout for the GRU: xwt[group 0..7][t 0..255][gatecol 0..191][rb 0..15]
__global__ __launch_bounds__(192) void xw_kernel(const float* __restrict__ x,
                                                 const float* __restrict__ mask,
                                                 const float* __restrict__ delta,
                                                 const float* __restrict__ w_ih,
                                                 const float* __restrict__ b_ih,
                                                 float* __restrict__ xwt) {
    __shared__ float inp[16][120];
    __shared__ float wl[192][21];
    int group = blockIdx.x >> 8;
    int t = blockIdx.x & 255;
    int tid = threadIdx.x;

    for (int idx = tid; idx < 16 * 120; idx += 192) {
        int r = idx / 120, k = idx % 120;
        size_t g = (size_t)(group * 16 + r) * 256 + t;
        float v;
        if (k < 40)      v = x[g * FIN + k];
        else if (k < 80) v = mask[g * FIN + (k - 40)];
        else             v = delta[g * FIN + (k - 80)];
        inp[r][k] = v;
    }

    float acc[16];
#pragma unroll
    for (int r = 0; r < 16; ++r) acc[r] = 0.f;

    for (int kt = 0; kt < 6; ++kt) {
        __syncthreads();
        for (int idx = tid; idx < 192 * 20; idx += 192) {
            int r = idx / 20, k = idx % 20;
            wl[r][k] = w_ih[(size_t)r * 120 + kt * 20 + k];
        }
        __syncthreads();
#pragma unroll
        for (int kk = 0; kk < 20; ++kk) {
            float w = wl[tid][kk];
            int kg = kt * 20 + kk;
#pragma unroll
            for (int r = 0; r < 16; ++r) acc[r] += w * inp[r][kg];
        }
    }
    float bias = b_ih[tid];
    float* o = xwt + ((size_t)(group * 256 + t) * 192 + tid) * 16;
#pragma unroll
    for (int r = 0; r < 16; r += 4) {
        float4 v = {acc[r] + bias, acc[r + 1] + bias, acc[r + 2] + bias, acc[r + 3] + bias};
        *(float4*)&o[r] = v;
    }
}

// ---------------------------------------------------------------- MFMA GRU scan v4
// 8 blocks x 16 batch rows, 4 waves. v3 fixed the barrier drain; v4 removes the LDS W-reads:
// the 6 W_hh fragments per lane are LOOP-INVARIANT and only 24 VGPRs -> load once from
// GLOBAL, convert to bf16 in-register. Per-step LDS = 2 ds_read_b128 (hb) + 4 ds_write_b16.
// (R9 PMC: active-CU VALUBusy ~54%, LDS pipe ~260cyc/step on W+h reads was the co-bottleneck.)
__device__ __forceinline__ float gru_gate(float xr, float xz, float xn,
                                          float ar, float az, float an, float hold) {
    float r  = 1.f / (1.f + __expf(-(xr + ar)));
    float zg = 1.f / (1.f + __expf(-(xz + az)));
    float nx = xn + r * an;
    float n  = 2.f / (1.f + __expf(-2.f * nx)) - 1.f;   // tanh
    return (1.f - zg) * n + zg * hold;
}

__global__ __launch_bounds__(256, 1) void gru_scan_kernel(const float* __restrict__ w_hh,
                                                          const float* __restrict__ b_hh,
                                                          const float* __restrict__ xwt,
                                                          u16* __restrict__ hsb) {
    __shared__ __align__(16) u16 hb[2][16 * 64];   // bf16 h A-frag source, slot^(row&7) swizzled
    int b0 = blockIdx.x * 16;
    int tid = threadIdx.x;
    int w = tid >> 6, lane = tid & 63;
    int fr = lane & 15, hi = lane >> 4;

    for (int idx = tid; idx < 1024; idx += 256) hb[0][idx] = 0;

    int c = w * 16 + fr;                 // gate col / h col owned by this lane
    float br_ = b_hh[c], bz_ = b_hh[64 + c], bn_ = b_hh[128 + c];

    // W_hh B-fragments in registers (24 VGPRs, loop-invariant):
    // fragment elems = w_hh[row][slot*8 .. +8), slot = ks*4+hi, rows c / 64+c / 128+c.
    short8 wfr[2], wfz[2], wfn[2];
#pragma unroll
    for (int ks = 0; ks < 2; ++ks) {
        int slot = ks * 4 + hi;
        const float* p0 = w_hh + (size_t)c * 64 + slot * 8;
        const float* p1 = w_hh + (size_t)(64 + c) * 64 + slot * 8;
        const float* p2 = w_hh + (size_t)(128 + c) * 64 + slot * 8;
#pragma unroll
        for (int q = 0; q < 8; ++q) {
            wfr[ks][q] = (short)f2b(p0[q]);
            wfz[ks][q] = (short)f2b(p1[q]);
            wfn[ks][q] = (short)f2b(p2[q]);
        }
    }

    const float* xg = xwt + (size_t)blockIdx.x * (256 * 192 * 16);
    int lo = hi * 4;

    float hr0 = 0.f, hr1 = 0.f, hr2 = 0.f, hr3 = 0.f;   // h state, exclusive per lane

    int wo0 = (lo + 0) * 64 + ((((c >> 3) ^ ((lo + 0) & 7))) << 3) + (c & 7);
    int wo1 = (lo + 1) * 64 + ((((c >> 3) ^ ((lo + 1) & 7))) << 3) + (c & 7);
    int wo2 = (lo + 2) * 64 + ((((c >> 3) ^ ((lo + 2) & 7))) << 3) + (c & 7);
    int wo3 = (lo + 3) * 64 + ((((c >> 3) ^ ((lo + 3) & 7))) << 3) + (c & 7);
    size_t ho0 = ((size_t)(b0 + lo + 0) * SS) * 64 + c;
    size_t ho1 = ((size_t)(b0 + lo + 1) * SS) * 64 + c;
    size_t ho2 = ((size_t)(b0 + lo + 2) * SS) * 64 + c;
    size_t ho3 = ((size_t)(b0 + lo + 3) * SS) * 64 + c;

    // prologue: depth-2 prefetch (A=t0, B=t1)
    float4 axr = *(const float4*)&xg[((size_t)0 * 192 + c) * 16 + lo];
    float4 axz = *(const float4*)&xg[((size_t)0 * 192 + 64 + c) * 16 + lo];
    float4 axn = *(const float4*)&xg[((size_t)0 * 192 + 128 + c) * 16 + lo];
    float4 bxr = *(const float4*)&xg[((size_t)1 * 192 + c) * 16 + lo];
    float4 bxz = *(const float4*)&xg[((size_t)1 * 192 + 64 + c) * 16 + lo];
    float4 bxn = *(const float4*)&xg[((size_t)1 * 192 + 128 + c) * 16 + lo];
    __syncthreads();   // hb[0] visible

    int cur = 0;
    auto step = [&](float4 xr4, float4 xz4, float4 xn4, int t) {
        f32x4 ar = {br_, br_, br_, br_};
        f32x4 az = {bz_, bz_, bz_, bz_};
        f32x4 an = {bn_, bn_, bn_, bn_};
#pragma unroll
        for (int ks = 0; ks < 2; ++ks) {
            int soff = (((ks << 2) + hi) ^ (fr & 7)) << 3;
            short8 af = *(const short8*)&hb[cur][fr * 64 + soff];
            ar = __builtin_amdgcn_mfma_f32_16x16x32_bf16(af, wfr[ks], ar, 0, 0, 0);
            az = __builtin_amdgcn_mfma_f32_16x16x32_bf16(af, wfz[ks], az, 0, 0, 0);
            an = __builtin_amdgcn_mfma_f32_16x16x32_bf16(af, wfn[ks], an, 0, 0, 0);
        }
        hr0 = gru_gate(xr4.x, xz4.x, xn4.x, ar[0], az[0], an[0], hr0);
        hr1 = gru_gate(xr4.y, xz4.y, xn4.y, ar[1], az[1], an[1], hr1);
        hr2 = gru_gate(xr4.z, xz4.z, xn4.z, ar[2], az[2], an[2], hr2);
        hr3 = gru_gate(xr4.w, xz4.w, xn4.w, ar[3], az[3], an[3], hr3);
        u16 v0 = f2b(hr0), v1 = f2b(hr1), v2 = f2b(hr2), v3 = f2b(hr3);
        int nxt = cur ^ 1;
        hb[nxt][wo0] = v0; hb[nxt][wo1] = v1; hb[nxt][wo2] = v2; hb[nxt][wo3] = v3;
        hsb[ho0 + (size_t)t * 64] = v0;
        hsb[ho1 + (size_t)t * 64] = v1;
        hsb[ho2 + (size_t)t * 64] = v2;
        hsb[ho3 + (size_t)t * 64] = v3;
        // LDS-only drain + raw barrier: global prefetch loads stay in flight
        asm volatile("s_waitcnt lgkmcnt(0)\n\ts_barrier" ::: "memory");
        cur = nxt;
    };

    for (int t = 0; t < SS; t += 2) {
        {   // even step: consume A, refill A for t+2
            int tp = (t + 2 < SS) ? t + 2 : t;
            float4 nr = *(const float4*)&xg[((size_t)tp * 192 + c) * 16 + lo];
            float4 nz = *(const float4*)&xg[((size_t)tp * 192 + 64 + c) * 16 + lo];
            float4 nn = *(const float4*)&xg[((size_t)tp * 192 + 128 + c) * 16 + lo];
            step(axr, axz, axn, t);
            axr = nr; axz = nz; axn = nn;
        }
        {   // odd step: consume B, refill B for t+3
            int tp = (t + 3 < SS) ? t + 3 : t + 1;
            float4 nr = *(const float4*)&xg[((size_t)tp * 192 + c) * 16 + lo];
            float4 nz = *(const float4*)&xg[((size_t)tp * 192 + 64 + c) * 16 + lo];
            float4 nn = *(const float4*)&xg[((size_t)tp * 192 + 128 + c) * 16 + lo];
            step(bxr, bxz, bxn, t + 1);
            bxr = nr; bxz = nz; bxn = nn;
        }
    }
}

// ---------------------------------------------------------------- bf16 MFMA GEMM (BK=64, swizzled)
// MODE: 1=f32 C, 2=bf16 Cb, 3=both, 4=fused residual+LayerNorm (N==128, bn==0)
__device__ __forceinline__ void gl_lds16(const void* g, void* s) {
    __builtin_amdgcn_global_load_lds(
        (const __attribute__((address_space(1))) void*)g,
        (__attribute__((address_space(3))) void*)s, 16, 0, 0);
}

template <int MODE, bool RELU>
__global__ __launch_bounds__(256, 2) void mfma_gemm(const u16* __restrict__ A,
                                                    const u16* __restrict__ W,
                                                    const float* __restrict__ bias,
                                                    float* __restrict__ C,
                                                    u16* __restrict__ Cb,
                                                    const float* __restrict__ lns,
                                                    const float* __restrict__ lnb,
                                                    int M, int N, int K) {
    __shared__ __align__(16) u16 Al[128 * 64];
    __shared__ __align__(16) u16 Bl[128 * 64];
    __shared__ float lred[2][2][128];
    int bm = blockIdx.x, bn = blockIdx.y;
    int tid = threadIdx.x;
    int w = tid >> 6, lane = tid & 63;
    int wrow = (w >> 1) * 64, wcol = (w & 1) * 64;
    int fr = lane & 15, hi = lane >> 4;
    int rl = lane >> 3;
    int sl = lane & 7;
    int ssl = sl ^ rl;

    const u16* Ag = A + ((size_t)bm * 128) * K + ssl * 8;
    const u16* Wg = W + ((size_t)bn * 128) * K + ssl * 8;

    f32x4 acc[4][4];
#pragma unroll
    for (int i = 0; i < 4; ++i)
#pragma unroll
        for (int jj = 0; jj < 4; ++jj) acc[i][jj] = (f32x4){0.f, 0.f, 0.f, 0.f};

    int ar[4], br[4];
#pragma unroll
    for (int m = 0; m < 4; ++m) {
        ar[m] = (wrow + m * 16 + fr) * 64;
        br[m] = (wcol + m * 16 + fr) * 64;
    }
    int swz = (fr & 7);

    for (int kt = 0; kt < K; kt += 64) {
        __syncthreads();
#pragma unroll
        for (int i = 0; i < 4; ++i) {
            int c = w * 4 + i;
            int row = c * 8 + rl;
            gl_lds16(Ag + (size_t)row * K + kt, &Al[c * 512]);
            gl_lds16(Wg + (size_t)row * K + kt, &Bl[c * 512]);
        }
        __syncthreads();
#pragma unroll
        for (int kk = 0; kk < 2; ++kk) {
            short8 a[4], bq[4];
            int soff = (((kk << 2) + hi) ^ swz) << 3;
#pragma unroll
            for (int m = 0; m < 4; ++m)
                a[m] = *(const short8*)&Al[ar[m] + soff];
#pragma unroll
            for (int n = 0; n < 4; ++n)
                bq[n] = *(const short8*)&Bl[br[n] + soff];
#pragma unroll
            for (int m = 0; m < 4; ++m)
#pragma unroll
                for (int n = 0; n < 4; ++n)
                    acc[m][n] = __builtin_amdgcn_mfma_f32_16x16x32_bf16(a[m], bq[n], acc[m][n], 0, 0, 0);
        }
    }

    float bv[4];
#pragma unroll
    for (int n = 0; n < 4; ++n) bv[n] = bias[bn * 128 + wcol + n * 16 + fr];

    if (MODE == 4) {
        float v[4][4][4];
#pragma unroll
        for (int m = 0; m < 4; ++m)
#pragma unroll
            for (int j = 0; j < 4; ++j) {
                int row = bm * 128 + wrow + m * 16 + hi * 4 + j;
#pragma unroll
                for (int n = 0; n < 4; ++n)
                    v[m][n][j] = acc[m][n][j] + bv[n] + C[(size_t)row * 128 + wcol + n * 16 + fr];
            }
#pragma unroll
        for (int m = 0; m < 4; ++m)
#pragma unroll
            for (int j = 0; j < 4; ++j) {
                float s = v[m][0][j] + v[m][1][j] + v[m][2][j] + v[m][3][j];
                float q = v[m][0][j]*v[m][0][j] + v[m][1][j]*v[m][1][j]
                        + v[m][2][j]*v[m][2][j] + v[m][3][j]*v[m][3][j];
#pragma unroll
                for (int off = 1; off <= 8; off <<= 1) {
                    s += __shfl_xor(s, off);
                    q += __shfl_xor(q, off);
                }
                if (fr == 0) {
                    int lrow = wrow + m * 16 + hi * 4 + j;
                    lred[0][w & 1][lrow] = s;
                    lred[1][w & 1][lrow] = q;
                }
            }
        __syncthreads();
        float sv[4], bb[4];
#pragma unroll
        for (int n = 0; n < 4; ++n) {
            sv[n] = lns[wcol + n * 16 + fr];
            bb[n] = lnb[wcol + n * 16 + fr];
        }
#pragma unroll
        for (int m = 0; m < 4; ++m)
#pragma unroll
            for (int j = 0; j < 4; ++j) {
                int lrow = wrow + m * 16 + hi * 4 + j;
                float mean = (lred[0][0][lrow] + lred[0][1][lrow]) * (1.f / 128.f);
                float msq  = (lred[1][0][lrow] + lred[1][1][lrow]) * (1.f / 128.f);
                float rstd = rsqrtf(msq - mean * mean + 1e-5f);
                int row = bm * 128 + lrow;
#pragma unroll
                for (int n = 0; n < 4; ++n) {
                    int col = wcol + n * 16 + fr;
                    float o = (v[m][n][j] - mean) * rstd * sv[n] + bb[n];
                    C[(size_t)row * 128 + col] = o;
                    Cb[(size_t)row * 128 + col] = f2b(o);
                }
            }
    } else {
#pragma unroll
        for (int m = 0; m < 4; ++m) {
#pragma unroll
            for (int j = 0; j < 4; ++j) {
                int row = bm * 128 + wrow + m * 16 + hi * 4 + j;
#pragma unroll
                for (int n = 0; n < 4; ++n) {
                    int col = bn * 128 + wcol + n * 16 + fr;
                    float vv = acc[m][n][j] + bv[n];
                    if (RELU) vv = fmaxf(vv, 0.f);
                    if (MODE & 1) C[(size_t)row * N + col] = vv;
                    if (MODE & 2) Cb[(size_t)row * N + col] = f2b(vv);
                }
            }
        }
    }
}

// ---------------------------------------------------------------- fused FF: relu(zb@W1^T+b1)@W2^T+b2
// + residual + LN2, one block per 128 rows (grid 256 = 1 block/CU), no global ff buffer.
__global__ __launch_bounds__(256, 1) void ff_fused_kernel(const u16* __restrict__ zbin,
                                                          const u16* __restrict__ w1,
                                                          const float* __restrict__ b1,
                                                          const u16* __restrict__ w2,
                                                          const float* __restrict__ b2,
                                                          const float* __restrict__ lns,
                                                          const float* __restrict__ lnb,
                                                          float* __restrict__ z,
                                                          u16* __restrict__ zbout) {
    __shared__ __align__(16) u16 ZB[2][128 * 64];
    __shared__ __align__(16) u16 W1C[2][128 * 64];
    __shared__ __align__(16) u16 W2C[2][128 * 64];
    __shared__ __align__(16) u16 A1[2][128 * 64];
    __shared__ float lred[2][2][128];
    int bm = blockIdx.x;
    int tid = threadIdx.x;
    int w = tid >> 6, lane = tid & 63;
    int wrow = (w >> 1) * 64, wcol = (w & 1) * 64;
    int fr = lane & 15, hi = lane >> 4;
    int rl = lane >> 3, ssl = (lane & 7) ^ rl;
    int swz = fr & 7;
    int xh = wrow >> 6;

#pragma unroll
    for (int hk = 0; hk < 2; ++hk)
#pragma unroll
        for (int i = 0; i < 4; ++i) {
            int ch = w * 4 + i, row = ch * 8 + rl;
            gl_lds16(zbin + ((size_t)(bm * 128 + row)) * 128 + hk * 64 + ssl * 8, &ZB[hk][ch * 512]);
        }

    f32x4 acc2[4][4];
#pragma unroll
    for (int m = 0; m < 4; ++m)
#pragma unroll
        for (int n = 0; n < 4; ++n) acc2[m][n] = (f32x4){0.f, 0.f, 0.f, 0.f};

    for (int ci = 0; ci < 16; ++ci) {
#pragma unroll
        for (int hk = 0; hk < 2; ++hk)
#pragma unroll
            for (int i = 0; i < 4; ++i) {
                int ch = w * 4 + i, row = ch * 8 + rl;
                gl_lds16(w1 + ((size_t)(ci * 128 + row)) * 128 + hk * 64 + ssl * 8, &W1C[hk][ch * 512]);
                gl_lds16(w2 + ((size_t)row) * 2048 + ci * 128 + hk * 64 + ssl * 8, &W2C[hk][ch * 512]);
            }
        __syncthreads();

        f32x4 acc1[4][4];
#pragma unroll
        for (int m = 0; m < 4; ++m)
#pragma unroll
            for (int n = 0; n < 4; ++n) acc1[m][n] = (f32x4){0.f, 0.f, 0.f, 0.f};
#pragma unroll
        for (int ks = 0; ks < 4; ++ks) {
            int hk = ks >> 1;
            int soff = ((((ks & 1) << 2) + hi) ^ swz) << 3;
            short8 a[4], b[4];
#pragma unroll
            for (int m = 0; m < 4; ++m)
                a[m] = *(const short8*)&W1C[hk][(wrow + m * 16 + fr) * 64 + soff];
#pragma unroll
            for (int n = 0; n < 4; ++n)
                b[n] = *(const short8*)&ZB[hk][(wcol + n * 16 + fr) * 64 + soff];
#pragma unroll
            for (int m = 0; m < 4; ++m)
#pragma unroll
                for (int n = 0; n < 4; ++n)
                    acc1[m][n] = __builtin_amdgcn_mfma_f32_16x16x32_bf16(a[m], b[n], acc1[m][n], 0, 0, 0);
        }
#pragma unroll
        for (int m = 0; m < 4; ++m) {
            int x0 = wrow + m * 16 + hi * 4;
            float4 bb = *(const float4*)&b1[ci * 128 + x0];
            int slot = (x0 & 63) >> 3;
            int wadd = x0 & 7;
#pragma unroll
            for (int n = 0; n < 4; ++n) {
                int r = wcol + n * 16 + fr;
                float v0 = fmaxf(acc1[m][n][0] + bb.x, 0.f);
                float v1 = fmaxf(acc1[m][n][1] + bb.y, 0.f);
                float v2 = fmaxf(acc1[m][n][2] + bb.z, 0.f);
                float v3 = fmaxf(acc1[m][n][3] + bb.w, 0.f);
                uint2 pk;
                pk.x = (unsigned)f2b(v0) | ((unsigned)f2b(v1) << 16);
                pk.y = (unsigned)f2b(v2) | ((unsigned)f2b(v3) << 16);
                *(uint2*)&A1[xh][r * 64 + ((slot ^ (r & 7)) << 3) + wadd] = pk;
            }
        }
        __syncthreads();

#pragma unroll
        for (int ks = 0; ks < 4; ++ks) {
            int hk = ks >> 1;
            int soff = ((((ks & 1) << 2) + hi) ^ swz) << 3;
            short8 a[4], b[4];
#pragma unroll
            for (int m = 0; m < 4; ++m)
                a[m] = *(const short8*)&W2C[hk][(wrow + m * 16 + fr) * 64 + soff];
#pragma unroll
            for (int n = 0; n < 4; ++n)
                b[n] = *(const short8*)&A1[hk][(wcol + n * 16 + fr) * 64 + soff];
#pragma unroll
            for (int m = 0; m < 4; ++m)
#pragma unroll
                for (int n = 0; n < 4; ++n)
                    acc2[m][n] = __builtin_amdgcn_mfma_f32_16x16x32_bf16(a[m], b[n], acc2[m][n], 0, 0, 0);
        }
        __syncthreads();
    }

    float vv[4][4][4];
#pragma unroll
    for (int m = 0; m < 4; ++m) {
        int x0 = wrow + m * 16 + hi * 4;
        float4 bb = *(const float4*)&b2[x0];
#pragma unroll
        for (int n = 0; n < 4; ++n) {
            int y = wcol + n * 16 + fr;
            float4 zo = *(const float4*)&z[((size_t)(bm * 128 + y)) * 128 + x0];
            vv[m][n][0] = acc2[m][n][0] + bb.x + zo.x;
            vv[m][n][1] = acc2[m][n][1] + bb.y + zo.y;
            vv[m][n][2] = acc2[m][n][2] + bb.z + zo.z;
            vv[m][n][3] = acc2[m][n][3] + bb.w + zo.w;
        }
    }
#pragma unroll
    for (int n = 0; n < 4; ++n) {
        float s = 0.f, q = 0.f;
#pragma unroll
        for (int m = 0; m < 4; ++m)
#pragma unroll
            for (int j = 0; j < 4; ++j) { float v = vv[m][n][j]; s += v; q += v * v; }
        s += __shfl_xor(s, 16); s += __shfl_xor(s, 32);
        q += __shfl_xor(q, 16); q += __shfl_xor(q, 32);
        if (hi == 0) {
            int y = wcol + n * 16 + fr;
            lred[0][xh][y] = s;
            lred[1][xh][y] = q;
        }
    }
    __syncthreads();
#pragma unroll
    for (int n = 0; n < 4; ++n) {
        int y = wcol + n * 16 + fr;
        float mean = (lred[0][0][y] + lred[0][1][y]) * (1.f / 128.f);
        float msq  = (lred[1][0][y] + lred[1][1][y]) * (1.f / 128.f);
        float rstd = rsqrtf(msq - mean * mean + 1e-5f);
#pragma unroll
        for (int m = 0; m < 4; ++m) {
            int x0 = wrow + m * 16 + hi * 4;
            float4 sv = *(const float4*)&lns[x0];
            float4 bv = *(const float4*)&lnb[x0];
            float o0 = (vv[m][n][0] - mean) * rstd * sv.x + bv.x;
            float o1 = (vv[m][n][1] - mean) * rstd * sv.y + bv.y;
            float o2 = (vv[m][n][2] - mean) * rstd * sv.z + bv.z;
            float o3 = (vv[m][n][3] - mean) * rstd * sv.w + bv.w;
            size_t zoff = ((size_t)(bm * 128 + y)) * 128 + x0;
            *(float4*)&z[zoff] = (float4){o0, o1, o2, o3};
            uint2 pk;
            pk.x = (unsigned)f2b(o0) | ((unsigned)f2b(o1) << 16);
            pk.y = (unsigned)f2b(o2) | ((unsigned)f2b(o3) << 16);
            *(uint2*)&zbout[zoff] = pk;
        }
    }
}

// ---------------------------------------------------------------- attention (bf16 qkv in, bf16 out)
__global__ __launch_bounds__(256) void attn_kernel(const u16* __restrict__ qkv,
                                                   const float* __restrict__ tm,
                                                   u16* __restrict__ attno) {
    int bh = blockIdx.x;
    int b = bh / NHH, hd = bh % NHH;
    int s = threadIdx.x;

    __shared__ float Kt[64][32];
    __shared__ float Vt[64][32];
    __shared__ float tms[64];

    float q[32];
    const u16* qrow = qkv + ((size_t)b * SS + s) * 384 + hd * 32;
#pragma unroll
    for (int j = 0; j < 32; j += 8) {
        short8 v = *(const short8*)&qrow[j];
#pragma unroll
        for (int jj = 0; jj < 8; ++jj) q[j + jj] = b2f((u16)v[jj]);
    }
    const float scale = 0.17677669529663687f;
    float denom = 0.f;
    float o[32];
#pragma unroll
    for (int j = 0; j < 32; ++j) o[j] = 0.f;

    for (int kt = 0; kt < SS; kt += 64) {
        __syncthreads();
        {
            int r = s >> 2, c = (s & 3) * 8;
            const u16* kb = qkv + ((size_t)b * SS + kt + r) * 384 + 128 + hd * 32 + c;
            const u16* vb = qkv + ((size_t)b * SS + kt + r) * 384 + 256 + hd * 32 + c;
            short8 kv = *(const short8*)kb;
            short8 vvv = *(const short8*)vb;
#pragma unroll
            for (int jj = 0; jj < 8; ++jj) {
                Kt[r][c + jj] = b2f((u16)kv[jj]);
                Vt[r][c + jj] = b2f((u16)vvv[jj]);
            }
        }
        if (s < 64) tms[s] = tm[b * SS + kt + s];
        __syncthreads();
        for (int k = 0; k < 64; ++k) {
            float acc = 0.f;
#pragma unroll
            for (int j = 0; j < 32; ++j) acc += q[j] * Kt[k][j];
            float sc = acc * scale + (tms[k] > 0.f ? 0.f : NEGV);
            float e = __expf(sc);
            denom += e;
#pragma unroll
            for (int j = 0; j < 32; ++j) o[j] += e * Vt[k][j];
        }
    }
    float inv = 1.f / denom;
    u16* orow = attno + ((size_t)b * SS + s) * DD + hd * 32;
#pragma unroll
    for (int j = 0; j < 32; j += 8) {
        short8 ov;
#pragma unroll
        for (int jj = 0; jj < 8; ++jj) ov[jj] = (short)f2b(o[j + jj] * inv);
        *(short8*)&orow[j] = ov;
    }
}

// ---------------------------------------------------------------- score = z @ score_w^T + b (masked)
__global__ __launch_bounds__(256) void score_kernel(const float* __restrict__ z,
                                                    const float* __restrict__ score_w,
                                                    const float* __restrict__ score_b,
                                                    const float* __restrict__ tm,
                                                    float* __restrict__ scores) {
    int row = blockIdx.x * 64 + (threadIdx.x >> 2);
    int c = threadIdx.x & 3;
    const float* zr = z + (size_t)row * DD + c * 32;
    const float* wr = score_w + c * 32;
    float acc = 0.f;
#pragma unroll
    for (int j = 0; j < 32; j += 4) {
        float4 a = *(const float4*)(zr + j), w = *(const float4*)(wr + j);
        acc += a.x * w.x + a.y * w.y + a.z * w.z + a.w * w.w;
    }
    acc += __shfl_xor(acc, 1);
    acc += __shfl_xor(acc, 2);
    if (c == 0) {
        float sc = acc + score_b[0];
        scores[row] = (tm[row] > 0.f) ? sc : NEGV;
    }
}

// ---------------------------------------------------------------- softmax over S + weighted pool
__global__ __launch_bounds__(256) void pool_kernel(const float* __restrict__ z,
                                                   const float* __restrict__ scores,
                                                   float* __restrict__ pooled) {
    int b = blockIdx.x;
    int tid = threadIdx.x;
    __shared__ float al[SS];
    __shared__ float red[8];
    __shared__ float pp[2][128];

    float sc = scores[b * SS + tid];
    float m = sc;
#pragma unroll
    for (int off = 32; off; off >>= 1) m = fmaxf(m, __shfl_xor(m, off));
    if ((tid & 63) == 0) red[tid >> 6] = m;
    __syncthreads();
    m = fmaxf(fmaxf(red[0], red[1]), fmaxf(red[2], red[3]));
    float e = __expf(sc - m);
    float ssum = e;
#pragma unroll
    for (int off = 32; off; off >>= 1) ssum += __shfl_xor(ssum, off);
    if ((tid & 63) == 0) red[4 + (tid >> 6)] = ssum;
    __syncthreads();
    ssum = red[4] + red[5] + red[6] + red[7];
    al[tid] = e / ssum;
    __syncthreads();

    int d = tid & 127, half = tid >> 7;
    float acc = 0.f;
    for (int t = half; t < SS; t += 2) acc += al[t] * z[((size_t)b * SS + t) * DD + d];
    pp[half][d] = acc;
    __syncthreads();
    if (tid < 128) pooled[b * 128 + tid] = pp[0][tid] + pp[1][tid];
}

// ---------------------------------------------------------------- routed heads
__global__ __launch_bounds__(128) void head_kernel(const float* __restrict__ pooled,
                                                   const float* __restrict__ reg_w,
                                                   const float* __restrict__ reg_b,
                                                   const float* __restrict__ bin_w,
                                                   const float* __restrict__ bin_b,
                                                   const int* __restrict__ wid,
                                                   float* __restrict__ out) {
    int b = blockIdx.x, tid = threadIdx.x;
    __shared__ float p[128];
    p[tid] = pooled[b * 128 + tid];
    __syncthreads();
    if (tid < 9) {
        int w = wid[b];
        const float* wrow;
        float bias;
        if (tid < 8) { wrow = reg_w + ((size_t)w * 8 + tid) * 128; bias = reg_b[w * 8 + tid]; }
        else         { wrow = bin_w + (size_t)w * 128;             bias = bin_b[w]; }
        float acc = bias;
        for (int k = 0; k < 128; ++k) acc += wrow[k] * p[k];
        if (tid < 8) out[b * 8 + tid] = acc;
        else         out[1024 + b] = acc;
    }
}

// ================================================================ host
extern "C" void kernel_launch(void* const* d_in, const int* in_sizes, int n_in,
                              void* d_out, int out_size, void* d_ws, size_t ws_size,
                              hipStream_t stream) {
    const float* x         = (const float*)d_in[0];
    const float* mask      = (const float*)d_in[1];
    const float* delta     = (const float*)d_in[2];
    const float* gru_w_ih  = (const float*)d_in[3];
    const float* gru_w_hh  = (const float*)d_in[4];
    const float* gru_b_ih  = (const float*)d_in[5];
    const float* gru_b_hh  = (const float*)d_in[6];
    const float* dm_w      = (const float*)d_in[7];
    const float* dm_b      = (const float*)d_in[8];
    const float* in_proj_w = (const float*)d_in[9];
    const float* in_proj_b = (const float*)d_in[10];
    const float* out_proj_w= (const float*)d_in[11];
    const float* out_proj_b= (const float*)d_in[12];
    const float* lin1_w    = (const float*)d_in[13];
    const float* lin1_b    = (const float*)d_in[14];
    const float* lin2_w    = (const float*)d_in[15];
    const float* lin2_b    = (const float*)d_in[16];
    const float* ln1_s     = (const float*)d_in[17];
    const float* ln1_bb    = (const float*)d_in[18];
    const float* ln2_s     = (const float*)d_in[19];
    const float* ln2_bb    = (const float*)d_in[20];
    const float* score_w   = (const float*)d_in[21];
    const float* score_b   = (const float*)d_in[22];
    const float* reg_w     = (const float*)d_in[23];
    const float* reg_b     = (const float*)d_in[24];
    const float* bin_w     = (const float*)d_in[25];
    const float* bin_b     = (const float*)d_in[26];
    const int*   window_id = (const int*)d_in[27];
    float* out = (float*)d_out;

    char* w8 = (char*)d_ws;
    float* z      = (float*)(w8 + 0);            // 16,777,216
    u16*   zb     = (u16*)  (w8 + 16777216);     //  8,388,608
    u16*   hsb    = (u16*)  (w8 + 25165824);     //  4,194,304
    u16*   wb_dm  = (u16*)  (w8 + 29360128);     //     16,384
    u16*   wb_ip  = (u16*)  (w8 + 29376512);     //    196,608
    u16*   wb_op  = (u16*)  (w8 + 29573120);     //     65,536
    u16*   wb_l1  = (u16*)  (w8 + 29638656);     //  1,048,576
    u16*   wb_l2  = (u16*)  (w8 + 30687232);     //  1,048,576
    float* tm     = (float*)(w8 + 31735808);     //    131,072
    float* scores = (float*)(w8 + 31866880);     //    131,072
    float* pooled = (float*)(w8 + 31997952);     //     65,536
    float* xwt    = (float*)(w8 + 32063488);     // 25,165,824 (GRU: xwt fp32 | later: qkvb bf16)
    u16*   qkvb   = (u16*)  (w8 + 32063488);
    u16*   attnob = (u16*)  (w8 + 57229312);     //  8,388,608   (total ~65.6MB)

    cvt_all_kernel<<<580, 256, 0, stream>>>(dm_w, in_proj_w, out_proj_w, lin1_w, lin2_w,
                                            wb_dm, wb_ip, wb_op, wb_l1, wb_l2);

    tm_kernel<<<(BB * SS + 255) / 256, 256, 0, stream>>>(mask, tm);
    xw_kernel<<<2048, 192, 0, stream>>>(x, mask, delta, gru_w_ih, gru_b_ih, xwt);
    gru_scan_kernel<<<8, 256, 0, stream>>>(gru_w_hh, gru_b_hh, xwt, hsb);

    mfma_gemm<3, false><<<dim3(256, 1), 256, 0, stream>>>(
        hsb, wb_dm, dm_b, z, zb, nullptr, nullptr, 32768, 128, 64);

    for (int l = 0; l < LL; ++l) {
        mfma_gemm<2, false><<<dim3(256, 3), 256, 0, stream>>>(
            zb, wb_ip + (size_t)l * 49152, in_proj_b + l * 384, nullptr, qkvb,
            nullptr, nullptr, 32768, 384, 128);
        attn_kernel<<<BB * NHH, 256, 0, stream>>>(qkvb, tm, attnob);
        mfma_gemm<4, false><<<dim3(256, 1), 256, 0, stream>>>(
            attnob, wb_op + (size_t)l * 16384, out_proj_b + l * 128, z, zb,
            ln1_s + l * 128, ln1_bb + l * 128, 32768, 128, 128);
        ff_fused_kernel<<<256, 256, 0, stream>>>(
            zb, wb_l1 + (size_t)l * 262144, lin1_b + l * 2048,
            wb_l2 + (size_t)l * 262144, lin2_b + l * 128,
            ln2_s + l * 128, ln2_bb + l * 128, z, zb);
    }

    score_kernel<<<BB * SS / 64, 256, 0, stream>>>(z, score_w, score_b, tm, scores);
    pool_kernel<<<BB, 256, 0, stream>>>(z, scores, pooled);
    head_kernel<<<BB, 128, 0, stream>>>(pooled, reg_w, reg_b, bin_w, bin_b, window_id, out);
}

// Round 11
// 561.743 us; speedup vs baseline: 1.2205x; 1.2205x over previous
//
#include <hip/hip_runtime.h>

typedef __attribute__((ext_vector_type(8))) short short8;
typedef __attribute__((ext_vector_type(4))) float f32x4;
typedef unsigned short u16;

#define BB   128
#define SS   256
#define FIN  40
#define HH   64
#define DD   128
#define NHH  4
#define LL   2
#define NEGV (-1e9f)

__device__ __forceinline__ u16 f2b(float f) {
    unsigned u = __float_as_uint(f);
    return (u16)((u + 0x7FFFu + ((u >> 16) & 1u)) >> 16);
}
__device__ __forceinline__ float b2f(u16 u) {
    return __uint_as_float(((unsigned)u) << 16);
}

// ---------------------------------------------------------------- merged fp32 -> bf16 weight convert
__global__ __launch_bounds__(256) void cvt_all_kernel(const float* __restrict__ dm_w,
                                                      const float* __restrict__ ip_w,
                                                      const float* __restrict__ op_w,
                                                      const float* __restrict__ l1_w,
                                                      const float* __restrict__ l2_w,
                                                      u16* __restrict__ o_dm, u16* __restrict__ o_ip,
                                                      u16* __restrict__ o_op, u16* __restrict__ o_l1,
                                                      u16* __restrict__ o_l2) {
    int blk = blockIdx.x;
    const float* s; u16* d; int off;
    if      (blk < 4)   { s = dm_w; d = o_dm; off = blk; }
    else if (blk < 52)  { s = ip_w; d = o_ip; off = blk - 4; }
    else if (blk < 68)  { s = op_w; d = o_op; off = blk - 52; }
    else if (blk < 324) { s = l1_w; d = o_l1; off = blk - 68; }
    else                { s = l2_w; d = o_l2; off = blk - 324; }
    int i = (off * 256 + threadIdx.x) * 8;
    float4 a = *(const float4*)&s[i];
    float4 b = *(const float4*)&s[i + 4];
    short8 o;
    o[0] = (short)f2b(a.x); o[1] = (short)f2b(a.y); o[2] = (short)f2b(a.z); o[3] = (short)f2b(a.w);
    o[4] = (short)f2b(b.x); o[5] = (short)f2b(b.y); o[6] = (short)f2b(b.z); o[7] = (short)f2b(b.w);
    *(short8*)&d[i] = o;
}

// ---------------------------------------------------------------- time mask
__global__ __launch_bounds__(256) void tm_kernel(const float* __restrict__ mask,
                                                 float* __restrict__ tm) {
    int i = blockIdx.x * blockDim.x + threadIdx.x;
    if (i >= BB * SS) return;
    const float* m = mask + (size_t)i * FIN;
    float s = 0.f;
    for (int f = 0; f < FIN; ++f) s += m[f];
    tm[i] = (s > 0.f) ? 1.f : 0.f;
}

// ------------------------------------------------- xwt = concat(x,mask,delta) @ W_ih^T + b_ih
// TRANSPOSED output layout for the GRU: xwt[group 0..7][t 0..255][gatecol 0..191][rb 0..15]
__global__ __launch_bounds__(192) void xw_kernel(const float* __restrict__ x,
                                                 const float* __restrict__ mask,
                                                 const float* __restrict__ delta,
                                                 const float* __restrict__ w_ih,
                                                 const float* __restrict__ b_ih,
                                                 float* __restrict__ xwt) {
    __shared__ float inp[16][120];
    __shared__ float wl[192][21];
    int group = blockIdx.x >> 8;
    int t = blockIdx.x & 255;
    int tid = threadIdx.x;

    for (int idx = tid; idx < 16 * 120; idx += 192) {
        int r = idx / 120, k = idx % 120;
        size_t g = (size_t)(group * 16 + r) * 256 + t;
        float v;
        if (k < 40)      v = x[g * FIN + k];
        else if (k < 80) v = mask[g * FIN + (k - 40)];
        else             v = delta[g * FIN + (k - 80)];
        inp[r][k] = v;
    }

    float acc[16];
#pragma unroll
    for (int r = 0; r < 16; ++r) acc[r] = 0.f;

    for (int kt = 0; kt < 6; ++kt) {
        __syncthreads();
        for (int idx = tid; idx < 192 * 20; idx += 192) {
            int r = idx / 20, k = idx % 20;
            wl[r][k] = w_ih[(size_t)r * 120 + kt * 20 + k];
        }
        __syncthreads();
#pragma unroll
        for (int kk = 0; kk < 20; ++kk) {
            float w = wl[tid][kk];
            int kg = kt * 20 + kk;
#pragma unroll
            for (int r = 0; r < 16; ++r) acc[r] += w * inp[r][kg];
        }
    }
    float bias = b_ih[tid];
    float* o = xwt + ((size_t)(group * 256 + t) * 192 + tid) * 16;
#pragma unroll
    for (int r = 0; r < 16; r += 4) {
        float4 v = {acc[r] + bias, acc[r + 1] + bias, acc[r + 2] + bias, acc[r + 3] + bias};
        *(float4*)&o[r] = v;
    }
}

// ---------------------------------------------------------------- MFMA GRU scan v4 (unchanged R10)
__device__ __forceinline__ float gru_gate(float xr, float xz, float xn,
                                          float ar, float az, float an, float hold) {
    float r  = 1.f / (1.f + __expf(-(xr + ar)));
    float zg = 1.f / (1.f + __expf(-(xz + az)));
    float nx = xn + r * an;
    float n  = 2.f / (1.f + __expf(-2.f * nx)) - 1.f;   // tanh
    return (1.f - zg) * n + zg * hold;
}

__global__ __launch_bounds__(256, 1) void gru_scan_kernel(const float* __restrict__ w_hh,
                                                          const float* __restrict__ b_hh,
                                                          const float* __restrict__ xwt,
                                                          u16* __restrict__ hsb) {
    __shared__ __align__(16) u16 hb[2][16 * 64];
    int b0 = blockIdx.x * 16;
    int tid = threadIdx.x;
    int w = tid >> 6, lane = tid & 63;
    int fr = lane & 15, hi = lane >> 4;

    for (int idx = tid; idx < 1024; idx += 256) hb[0][idx] = 0;

    int c = w * 16 + fr;
    float br_ = b_hh[c], bz_ = b_hh[64 + c], bn_ = b_hh[128 + c];

    short8 wfr[2], wfz[2], wfn[2];
#pragma unroll
    for (int ks = 0; ks < 2; ++ks) {
        int slot = ks * 4 + hi;
        const float* p0 = w_hh + (size_t)c * 64 + slot * 8;
        const float* p1 = w_hh + (size_t)(64 + c) * 64 + slot * 8;
        const float* p2 = w_hh + (size_t)(128 + c) * 64 + slot * 8;
#pragma unroll
        for (int q = 0; q < 8; ++q) {
            wfr[ks][q] = (short)f2b(p0[q]);
            wfz[ks][q] = (short)f2b(p1[q]);
            wfn[ks][q] = (short)f2b(p2[q]);
        }
    }

    const float* xg = xwt + (size_t)blockIdx.x * (256 * 192 * 16);
    int lo = hi * 4;

    float hr0 = 0.f, hr1 = 0.f, hr2 = 0.f, hr3 = 0.f;

    int wo0 = (lo + 0) * 64 + ((((c >> 3) ^ ((lo + 0) & 7))) << 3) + (c & 7);
    int wo1 = (lo + 1) * 64 + ((((c >> 3) ^ ((lo + 1) & 7))) << 3) + (c & 7);
    int wo2 = (lo + 2) * 64 + ((((c >> 3) ^ ((lo + 2) & 7))) << 3) + (c & 7);
    int wo3 = (lo + 3) * 64 + ((((c >> 3) ^ ((lo + 3) & 7))) << 3) + (c & 7);
    size_t ho0 = ((size_t)(b0 + lo + 0) * SS) * 64 + c;
    size_t ho1 = ((size_t)(b0 + lo + 1) * SS) * 64 + c;
    size_t ho2 = ((size_t)(b0 + lo + 2) * SS) * 64 + c;
    size_t ho3 = ((size_t)(b0 + lo + 3) * SS) * 64 + c;

    float4 axr = *(const float4*)&xg[((size_t)0 * 192 + c) * 16 + lo];
    float4 axz = *(const float4*)&xg[((size_t)0 * 192 + 64 + c) * 16 + lo];
    float4 axn = *(const float4*)&xg[((size_t)0 * 192 + 128 + c) * 16 + lo];
    float4 bxr = *(const float4*)&xg[((size_t)1 * 192 + c) * 16 + lo];
    float4 bxz = *(const float4*)&xg[((size_t)1 * 192 + 64 + c) * 16 + lo];
    float4 bxn = *(const float4*)&xg[((size_t)1 * 192 + 128 + c) * 16 + lo];
    __syncthreads();

    int cur = 0;
    auto step = [&](float4 xr4, float4 xz4, float4 xn4, int t) {
        f32x4 ar = {br_, br_, br_, br_};
        f32x4 az = {bz_, bz_, bz_, bz_};
        f32x4 an = {bn_, bn_, bn_, bn_};
#pragma unroll
        for (int ks = 0; ks < 2; ++ks) {
            int soff = (((ks << 2) + hi) ^ (fr & 7)) << 3;
            short8 af = *(const short8*)&hb[cur][fr * 64 + soff];
            ar = __builtin_amdgcn_mfma_f32_16x16x32_bf16(af, wfr[ks], ar, 0, 0, 0);
            az = __builtin_amdgcn_mfma_f32_16x16x32_bf16(af, wfz[ks], az, 0, 0, 0);
            an = __builtin_amdgcn_mfma_f32_16x16x32_bf16(af, wfn[ks], an, 0, 0, 0);
        }
        hr0 = gru_gate(xr4.x, xz4.x, xn4.x, ar[0], az[0], an[0], hr0);
        hr1 = gru_gate(xr4.y, xz4.y, xn4.y, ar[1], az[1], an[1], hr1);
        hr2 = gru_gate(xr4.z, xz4.z, xn4.z, ar[2], az[2], an[2], hr2);
        hr3 = gru_gate(xr4.w, xz4.w, xn4.w, ar[3], az[3], an[3], hr3);
        u16 v0 = f2b(hr0), v1 = f2b(hr1), v2 = f2b(hr2), v3 = f2b(hr3);
        int nxt = cur ^ 1;
        hb[nxt][wo0] = v0; hb[nxt][wo1] = v1; hb[nxt][wo2] = v2; hb[nxt][wo3] = v3;
        hsb[ho0 + (size_t)t * 64] = v0;
        hsb[ho1 + (size_t)t * 64] = v1;
        hsb[ho2 + (size_t)t * 64] = v2;
        hsb[ho3 + (size_t)t * 64] = v3;
        asm volatile("s_waitcnt lgkmcnt(0)\n\ts_barrier" ::: "memory");
        cur = nxt;
    };

    for (int t = 0; t < SS; t += 2) {
        {
            int tp = (t + 2 < SS) ? t + 2 : t;
            float4 nr = *(const float4*)&xg[((size_t)tp * 192 + c) * 16 + lo];
            float4 nz = *(const float4*)&xg[((size_t)tp * 192 + 64 + c) * 16 + lo];
            float4 nn = *(const float4*)&xg[((size_t)tp * 192 + 128 + c) * 16 + lo];
            step(axr, axz, axn, t);
            axr = nr; axz = nz; axn = nn;
        }
        {
            int tp = (t + 3 < SS) ? t + 3 : t + 1;
            float4 nr = *(const float4*)&xg[((size_t)tp * 192 + c) * 16 + lo];
            float4 nz = *(const float4*)&xg[((size_t)tp * 192 + 64 + c) * 16 + lo];
            float4 nn = *(const float4*)&xg[((size_t)tp * 192 + 128 + c) * 16 + lo];
            step(bxr, bxz, bxn, t + 1);
            bxr = nr; bxz = nz; bxn = nn;
        }
    }
}

// ---------------------------------------------------------------- bf16 MFMA GEMM (BK=64, swizzled)
__device__ __forceinline__ void gl_lds16(const void* g, void* s) {
    __builtin_amdgcn_global_load_lds(
        (const __attribute__((address_space(1))) void*)g,
        (__attribute__((address_space(3))) void*)s, 16, 0, 0);
}

template <int MODE, bool RELU>
__global__ __launch_bounds__(256, 2) void mfma_gemm(const u16* __restrict__ A,
                                                    const u16* __restrict__ W,
                                                    const float* __restrict__ bias,
                                                    float* __restrict__ C,
                                                    u16* __restrict__ Cb,
                                                    const float* __restrict__ lns,
                                                    const float* __restrict__ lnb,
                                                    int M, int N, int K) {
    __shared__ __align__(16) u16 Al[128 * 64];
    __shared__ __align__(16) u16 Bl[128 * 64];
    __shared__ float lred[2][2][128];
    int bm = blockIdx.x, bn = blockIdx.y;
    int tid = threadIdx.x;
    int w = tid >> 6, lane = tid & 63;
    int wrow = (w >> 1) * 64, wcol = (w & 1) * 64;
    int fr = lane & 15, hi = lane >> 4;
    int rl = lane >> 3;
    int sl = lane & 7;
    int ssl = sl ^ rl;

    const u16* Ag = A + ((size_t)bm * 128) * K + ssl * 8;
    const u16* Wg = W + ((size_t)bn * 128) * K + ssl * 8;

    f32x4 acc[4][4];
#pragma unroll
    for (int i = 0; i < 4; ++i)
#pragma unroll
        for (int jj = 0; jj < 4; ++jj) acc[i][jj] = (f32x4){0.f, 0.f, 0.f, 0.f};

    int ar[4], br[4];
#pragma unroll
    for (int m = 0; m < 4; ++m) {
        ar[m] = (wrow + m * 16 + fr) * 64;
        br[m] = (wcol + m * 16 + fr) * 64;
    }
    int swz = (fr & 7);

    for (int kt = 0; kt < K; kt += 64) {
        __syncthreads();
#pragma unroll
        for (int i = 0; i < 4; ++i) {
            int c = w * 4 + i;
            int row = c * 8 + rl;
            gl_lds16(Ag + (size_t)row * K + kt, &Al[c * 512]);
            gl_lds16(Wg + (size_t)row * K + kt, &Bl[c * 512]);
        }
        __syncthreads();
#pragma unroll
        for (int kk = 0; kk < 2; ++kk) {
            short8 a[4], bq[4];
            int soff = (((kk << 2) + hi) ^ swz) << 3;
#pragma unroll
            for (int m = 0; m < 4; ++m)
                a[m] = *(const short8*)&Al[ar[m] + soff];
#pragma unroll
            for (int n = 0; n < 4; ++n)
                bq[n] = *(const short8*)&Bl[br[n] + soff];
#pragma unroll
            for (int m = 0; m < 4; ++m)
#pragma unroll
                for (int n = 0; n < 4; ++n)
                    acc[m][n] = __builtin_amdgcn_mfma_f32_16x16x32_bf16(a[m], bq[n], acc[m][n], 0, 0, 0);
        }
    }

    float bv[4];
#pragma unroll
    for (int n = 0; n < 4; ++n) bv[n] = bias[bn * 128 + wcol + n * 16 + fr];

    if (MODE == 4) {
        float v[4][4][4];
#pragma unroll
        for (int m = 0; m < 4; ++m)
#pragma unroll
            for (int j = 0; j < 4; ++j) {
                int row = bm * 128 + wrow + m * 16 + hi * 4 + j;
#pragma unroll
                for (int n = 0; n < 4; ++n)
                    v[m][n][j] = acc[m][n][j] + bv[n] + C[(size_t)row * 128 + wcol + n * 16 + fr];
            }
#pragma unroll
        for (int m = 0; m < 4; ++m)
#pragma unroll
            for (int j = 0; j < 4; ++j) {
                float s = v[m][0][j] + v[m][1][j] + v[m][2][j] + v[m][3][j];
                float q = v[m][0][j]*v[m][0][j] + v[m][1][j]*v[m][1][j]
                        + v[m][2][j]*v[m][2][j] + v[m][3][j]*v[m][3][j];
#pragma unroll
                for (int off = 1; off <= 8; off <<= 1) {
                    s += __shfl_xor(s, off);
                    q += __shfl_xor(q, off);
                }
                if (fr == 0) {
                    int lrow = wrow + m * 16 + hi * 4 + j;
                    lred[0][w & 1][lrow] = s;
                    lred[1][w & 1][lrow] = q;
                }
            }
        __syncthreads();
        float sv[4], bb[4];
#pragma unroll
        for (int n = 0; n < 4; ++n) {
            sv[n] = lns[wcol + n * 16 + fr];
            bb[n] = lnb[wcol + n * 16 + fr];
        }
#pragma unroll
        for (int m = 0; m < 4; ++m)
#pragma unroll
            for (int j = 0; j < 4; ++j) {
                int lrow = wrow + m * 16 + hi * 4 + j;
                float mean = (lred[0][0][lrow] + lred[0][1][lrow]) * (1.f / 128.f);
                float msq  = (lred[1][0][lrow] + lred[1][1][lrow]) * (1.f / 128.f);
                float rstd = rsqrtf(msq - mean * mean + 1e-5f);
                int row = bm * 128 + lrow;
#pragma unroll
                for (int n = 0; n < 4; ++n) {
                    int col = wcol + n * 16 + fr;
                    float o = (v[m][n][j] - mean) * rstd * sv[n] + bb[n];
                    C[(size_t)row * 128 + col] = o;
                    Cb[(size_t)row * 128 + col] = f2b(o);
                }
            }
    } else {
#pragma unroll
        for (int m = 0; m < 4; ++m) {
#pragma unroll
            for (int j = 0; j < 4; ++j) {
                int row = bm * 128 + wrow + m * 16 + hi * 4 + j;
#pragma unroll
                for (int n = 0; n < 4; ++n) {
                    int col = bn * 128 + wcol + n * 16 + fr;
                    float vv = acc[m][n][j] + bv[n];
                    if (RELU) vv = fmaxf(vv, 0.f);
                    if (MODE & 1) C[(size_t)row * N + col] = vv;
                    if (MODE & 2) Cb[(size_t)row * N + col] = f2b(vv);
                }
            }
        }
    }
}

// ---------------------------------------------------------------- fused FF (unchanged R10)
__global__ __launch_bounds__(256, 1) void ff_fused_kernel(const u16* __restrict__ zbin,
                                                          const u16* __restrict__ w1,
                                                          const float* __restrict__ b1,
                                                          const u16* __restrict__ w2,
                                                          const float* __restrict__ b2,
                                                          const float* __restrict__ lns,
                                                          const float* __restrict__ lnb,
                                                          float* __restrict__ z,
                                                          u16* __restrict__ zbout) {
    __shared__ __align__(16) u16 ZB[2][128 * 64];
    __shared__ __align__(16) u16 W1C[2][128 * 64];
    __shared__ __align__(16) u16 W2C[2][128 * 64];
    __shared__ __align__(16) u16 A1[2][128 * 64];
    __shared__ float lred[2][2][128];
    int bm = blockIdx.x;
    int tid = threadIdx.x;
    int w = tid >> 6, lane = tid & 63;
    int wrow = (w >> 1) * 64, wcol = (w & 1) * 64;
    int fr = lane & 15, hi = lane >> 4;
    int rl = lane >> 3, ssl = (lane & 7) ^ rl;
    int swz = fr & 7;
    int xh = wrow >> 6;

#pragma unroll
    for (int hk = 0; hk < 2; ++hk)
#pragma unroll
        for (int i = 0; i < 4; ++i) {
            int ch = w * 4 + i, row = ch * 8 + rl;
            gl_lds16(zbin + ((size_t)(bm * 128 + row)) * 128 + hk * 64 + ssl * 8, &ZB[hk][ch * 512]);
        }

    f32x4 acc2[4][4];
#pragma unroll
    for (int m = 0; m < 4; ++m)
#pragma unroll
        for (int n = 0; n < 4; ++n) acc2[m][n] = (f32x4){0.f, 0.f, 0.f, 0.f};

    for (int ci = 0; ci < 16; ++ci) {
#pragma unroll
        for (int hk = 0; hk < 2; ++hk)
#pragma unroll
            for (int i = 0; i < 4; ++i) {
                int ch = w * 4 + i, row = ch * 8 + rl;
                gl_lds16(w1 + ((size_t)(ci * 128 + row)) * 128 + hk * 64 + ssl * 8, &W1C[hk][ch * 512]);
                gl_lds16(w2 + ((size_t)row) * 2048 + ci * 128 + hk * 64 + ssl * 8, &W2C[hk][ch * 512]);
            }
        __syncthreads();

        f32x4 acc1[4][4];
#pragma unroll
        for (int m = 0; m < 4; ++m)
#pragma unroll
            for (int n = 0; n < 4; ++n) acc1[m][n] = (f32x4){0.f, 0.f, 0.f, 0.f};
#pragma unroll
        for (int ks = 0; ks < 4; ++ks) {
            int hk = ks >> 1;
            int soff = ((((ks & 1) << 2) + hi) ^ swz) << 3;
            short8 a[4], b[4];
#pragma unroll
            for (int m = 0; m < 4; ++m)
                a[m] = *(const short8*)&W1C[hk][(wrow + m * 16 + fr) * 64 + soff];
#pragma unroll
            for (int n = 0; n < 4; ++n)
                b[n] = *(const short8*)&ZB[hk][(wcol + n * 16 + fr) * 64 + soff];
#pragma unroll
            for (int m = 0; m < 4; ++m)
#pragma unroll
                for (int n = 0; n < 4; ++n)
                    acc1[m][n] = __builtin_amdgcn_mfma_f32_16x16x32_bf16(a[m], b[n], acc1[m][n], 0, 0, 0);
        }
#pragma unroll
        for (int m = 0; m < 4; ++m) {
            int x0 = wrow + m * 16 + hi * 4;
            float4 bb = *(const float4*)&b1[ci * 128 + x0];
            int slot = (x0 & 63) >> 3;
            int wadd = x0 & 7;
#pragma unroll
            for (int n = 0; n < 4; ++n) {
                int r = wcol + n * 16 + fr;
                float v0 = fmaxf(acc1[m][n][0] + bb.x, 0.f);
                float v1 = fmaxf(acc1[m][n][1] + bb.y, 0.f);
                float v2 = fmaxf(acc1[m][n][2] + bb.z, 0.f);
                float v3 = fmaxf(acc1[m][n][3] + bb.w, 0.f);
                uint2 pk;
                pk.x = (unsigned)f2b(v0) | ((unsigned)f2b(v1) << 16);
                pk.y = (unsigned)f2b(v2) | ((unsigned)f2b(v3) << 16);
                *(uint2*)&A1[xh][r * 64 + ((slot ^ (r & 7)) << 3) + wadd] = pk;
            }
        }
        __syncthreads();

#pragma unroll
        for (int ks = 0; ks < 4; ++ks) {
            int hk = ks >> 1;
            int soff = ((((ks & 1) << 2) + hi) ^ swz) << 3;
            short8 a[4], b[4];
#pragma unroll
            for (int m = 0; m < 4; ++m)
                a[m] = *(const short8*)&W2C[hk][(wrow + m * 16 + fr) * 64 + soff];
#pragma unroll
            for (int n = 0; n < 4; ++n)
                b[n] = *(const short8*)&A1[hk][(wcol + n * 16 + fr) * 64 + soff];
#pragma unroll
            for (int m = 0; m < 4; ++m)
#pragma unroll
                for (int n = 0; n < 4; ++n)
                    acc2[m][n] = __builtin_amdgcn_mfma_f32_16x16x32_bf16(a[m], b[n], acc2[m][n], 0, 0, 0);
        }
        __syncthreads();
    }

    float vv[4][4][4];
#pragma unroll
    for (int m = 0; m < 4; ++m) {
        int x0 = wrow + m * 16 + hi * 4;
        float4 bb = *(const float4*)&b2[x0];
#pragma unroll
        for (int n = 0; n < 4; ++n) {
            int y = wcol + n * 16 + fr;
            float4 zo = *(const float4*)&z[((size_t)(bm * 128 + y)) * 128 + x0];
            vv[m][n][0] = acc2[m][n][0] + bb.x + zo.x;
            vv[m][n][1] = acc2[m][n][1] + bb.y + zo.y;
            vv[m][n][2] = acc2[m][n][2] + bb.z + zo.z;
            vv[m][n][3] = acc2[m][n][3] + bb.w + zo.w;
        }
    }
#pragma unroll
    for (int n = 0; n < 4; ++n) {
        float s = 0.f, q = 0.f;
#pragma unroll
        for (int m = 0; m < 4; ++m)
#pragma unroll
            for (int j = 0; j < 4; ++j) { float v = vv[m][n][j]; s += v; q += v * v; }
        s += __shfl_xor(s, 16); s += __shfl_xor(s, 32);
        q += __shfl_xor(q, 16); q += __shfl_xor(q, 32);
        if (hi == 0) {
            int y = wcol + n * 16 + fr;
            lred[0][xh][y] = s;
            lred[1][xh][y] = q;
        }
    }
    __syncthreads();
#pragma unroll
    for (int n = 0; n < 4; ++n) {
        int y = wcol + n * 16 + fr;
        float mean = (lred[0][0][y] + lred[0][1][y]) * (1.f / 128.f);
        float msq  = (lred[1][0][y] + lred[1][1][y]) * (1.f / 128.f);
        float rstd = rsqrtf(msq - mean * mean + 1e-5f);
#pragma unroll
        for (int m = 0; m < 4; ++m) {
            int x0 = wrow + m * 16 + hi * 4;
            float4 sv = *(const float4*)&lns[x0];
            float4 bv = *(const float4*)&lnb[x0];
            float o0 = (vv[m][n][0] - mean) * rstd * sv.x + bv.x;
            float o1 = (vv[m][n][1] - mean) * rstd * sv.y + bv.y;
            float o2 = (vv[m][n][2] - mean) * rstd * sv.z + bv.z;
            float o3 = (vv[m][n][3] - mean) * rstd * sv.w + bv.w;
            size_t zoff = ((size_t)(bm * 128 + y)) * 128 + x0;
            *(float4*)&z[zoff] = (float4){o0, o1, o2, o3};
            uint2 pk;
            pk.x = (unsigned)f2b(o0) | ((unsigned)f2b(o1) << 16);
            pk.y = (unsigned)f2b(o2) | ((unsigned)f2b(o3) << 16);
            *(uint2*)&zbout[zoff] = pk;
        }
    }
}

// ---------------------------------------------------------------- MFMA attention
// one block per (b,head): 512 blocks, 4 waves; wave w owns q rows [w*64, w*64+64).
// K staged [256][40] (pad-40: conflict-free b128 frag reads), V transposed [32][264],
// per-wave P tile [64][72]. No-max softmax (scores O(0.3); masked -> exp==0, matches the
// previously-passing scalar kernel). One barrier total; P write->read is same-wave
// (lgkmcnt(0) + memory clobber orders it, rule 18).
__global__ __launch_bounds__(256) void attn_mfma_kernel(const u16* __restrict__ qkv,
                                                        const float* __restrict__ tm,
                                                        u16* __restrict__ attno) {
    __shared__ __align__(16) u16 Kl[256 * 40];
    __shared__ __align__(16) u16 Vt[32 * 264];
    __shared__ __align__(16) u16 Pl[4][64 * 72];
    __shared__ float tmb[256];
    int bh = blockIdx.x;
    int b = bh >> 2, hd = bh & 3;
    int tid = threadIdx.x;
    int w = tid >> 6, lane = tid & 63;
    int fr = lane & 15, hi = lane >> 4;
    const u16* base = qkv + (size_t)b * SS * 384 + hd * 32;

    // stage K rows (coalesced b128 read+write)
    for (int idx = tid; idx < 1024; idx += 256) {
        int r = idx >> 2, s = idx & 3;
        short8 v = *(const short8*)(base + (size_t)r * 384 + 128 + s * 8);
        *(short8*)&Kl[r * 40 + s * 8] = v;
    }
    // stage V transposed (coalesced read, scalar transpose write)
    for (int idx = tid; idx < 1024; idx += 256) {
        int r = idx >> 2, s = idx & 3;
        short8 v = *(const short8*)(base + (size_t)r * 384 + 256 + s * 8);
#pragma unroll
        for (int q = 0; q < 8; ++q) Vt[(s * 8 + q) * 264 + r] = (u16)v[q];
    }
    tmb[tid] = (tm[b * SS + tid] > 0.f) ? 0.f : NEGV;

    // Q fragments in registers (A-frag: row=fr, elems=hi*8..+8 of D=32)
    int q0 = w * 64;
    short8 qf[4];
#pragma unroll
    for (int m = 0; m < 4; ++m)
        qf[m] = *(const short8*)(base + (size_t)(q0 + m * 16 + fr) * 384 + hi * 8);
    __syncthreads();

    const float scale = 0.17677669529663687f;
    f32x4 accO[4][2];
#pragma unroll
    for (int m = 0; m < 4; ++m) {
        accO[m][0] = (f32x4){0.f, 0.f, 0.f, 0.f};
        accO[m][1] = (f32x4){0.f, 0.f, 0.f, 0.f};
    }
    float den[4][4];
#pragma unroll
    for (int m = 0; m < 4; ++m)
#pragma unroll
        for (int j = 0; j < 4; ++j) den[m][j] = 0.f;

    u16* pw = &Pl[w][0];

    for (int kt = 0; kt < 4; ++kt) {
        // ---- S = Q K^T on this 64-k tile
        f32x4 accS[4][4];
#pragma unroll
        for (int m = 0; m < 4; ++m)
#pragma unroll
            for (int n = 0; n < 4; ++n) accS[m][n] = (f32x4){0.f, 0.f, 0.f, 0.f};
        short8 kf[4];
#pragma unroll
        for (int n = 0; n < 4; ++n)
            kf[n] = *(const short8*)&Kl[(kt * 64 + n * 16 + fr) * 40 + hi * 8];
#pragma unroll
        for (int m = 0; m < 4; ++m)
#pragma unroll
            for (int n = 0; n < 4; ++n)
                accS[m][n] = __builtin_amdgcn_mfma_f32_16x16x32_bf16(qf[m], kf[n], accS[m][n], 0, 0, 0);

        float bias[4];
#pragma unroll
        for (int n = 0; n < 4; ++n) bias[n] = tmb[kt * 64 + n * 16 + fr];

        // ---- exp + row-sum + P->bf16 LDS (C-layout: col=n*16+fr, row=m*16+hi*4+j)
#pragma unroll
        for (int m = 0; m < 4; ++m) {
            float rs0 = 0.f, rs1 = 0.f, rs2 = 0.f, rs3 = 0.f;
#pragma unroll
            for (int n = 0; n < 4; ++n) {
                float p0 = __expf(accS[m][n][0] * scale + bias[n]);
                float p1 = __expf(accS[m][n][1] * scale + bias[n]);
                float p2 = __expf(accS[m][n][2] * scale + bias[n]);
                float p3 = __expf(accS[m][n][3] * scale + bias[n]);
                rs0 += p0; rs1 += p1; rs2 += p2; rs3 += p3;
                int cb = n * 16 + fr;
                pw[(m * 16 + hi * 4 + 0) * 72 + cb] = f2b(p0);
                pw[(m * 16 + hi * 4 + 1) * 72 + cb] = f2b(p1);
                pw[(m * 16 + hi * 4 + 2) * 72 + cb] = f2b(p2);
                pw[(m * 16 + hi * 4 + 3) * 72 + cb] = f2b(p3);
            }
            // reduce across fr (lane bits 0-3)
#pragma unroll
            for (int off = 1; off <= 8; off <<= 1) {
                rs0 += __shfl_xor(rs0, off);
                rs1 += __shfl_xor(rs1, off);
                rs2 += __shfl_xor(rs2, off);
                rs3 += __shfl_xor(rs3, off);
            }
            den[m][0] += rs0; den[m][1] += rs1; den[m][2] += rs2; den[m][3] += rs3;
        }
        // order P writes before P reads (same wave; prevent compiler reordering)
        asm volatile("s_waitcnt lgkmcnt(0)" ::: "memory");

        // ---- O += P V  (A=P rows q, B=V^T rows d)
#pragma unroll
        for (int ks = 0; ks < 2; ++ks) {
            short8 pf[4], vf[2];
#pragma unroll
            for (int m = 0; m < 4; ++m)
                pf[m] = *(const short8*)&pw[(m * 16 + fr) * 72 + ks * 32 + hi * 8];
#pragma unroll
            for (int nd = 0; nd < 2; ++nd)
                vf[nd] = *(const short8*)&Vt[(nd * 16 + fr) * 264 + kt * 64 + ks * 32 + hi * 8];
#pragma unroll
            for (int m = 0; m < 4; ++m)
#pragma unroll
                for (int nd = 0; nd < 2; ++nd)
                    accO[m][nd] = __builtin_amdgcn_mfma_f32_16x16x32_bf16(pf[m], vf[nd], accO[m][nd], 0, 0, 0);
        }
    }

    // ---- normalize + store (C-layout rows match den's rows)
    u16* orow = attno + (size_t)(b * SS + q0) * DD + hd * 32;
#pragma unroll
    for (int m = 0; m < 4; ++m)
#pragma unroll
        for (int j = 0; j < 4; ++j) {
            float inv = 1.f / den[m][j];
            int qr = m * 16 + hi * 4 + j;
            orow[(size_t)qr * DD + fr]      = f2b(accO[m][0][j] * inv);
            orow[(size_t)qr * DD + 16 + fr] = f2b(accO[m][1][j] * inv);
        }
}

// ---------------------------------------------------------------- score = z @ score_w^T + b (masked)
__global__ __launch_bounds__(256) void score_kernel(const float* __restrict__ z,
                                                    const float* __restrict__ score_w,
                                                    const float* __restrict__ score_b,
                                                    const float* __restrict__ tm,
                                                    float* __restrict__ scores) {
    int row = blockIdx.x * 64 + (threadIdx.x >> 2);
    int c = threadIdx.x & 3;
    const float* zr = z + (size_t)row * DD + c * 32;
    const float* wr = score_w + c * 32;
    float acc = 0.f;
#pragma unroll
    for (int j = 0; j < 32; j += 4) {
        float4 a = *(const float4*)(zr + j), w = *(const float4*)(wr + j);
        acc += a.x * w.x + a.y * w.y + a.z * w.z + a.w * w.w;
    }
    acc += __shfl_xor(acc, 1);
    acc += __shfl_xor(acc, 2);
    if (c == 0) {
        float sc = acc + score_b[0];
        scores[row] = (tm[row] > 0.f) ? sc : NEGV;
    }
}

// ---------------------------------------------------------------- softmax over S + weighted pool
__global__ __launch_bounds__(256) void pool_kernel(const float* __restrict__ z,
                                                   const float* __restrict__ scores,
                                                   float* __restrict__ pooled) {
    int b = blockIdx.x;
    int tid = threadIdx.x;
    __shared__ float al[SS];
    __shared__ float red[8];
    __shared__ float pp[2][128];

    float sc = scores[b * SS + tid];
    float m = sc;
#pragma unroll
    for (int off = 32; off; off >>= 1) m = fmaxf(m, __shfl_xor(m, off));
    if ((tid & 63) == 0) red[tid >> 6] = m;
    __syncthreads();
    m = fmaxf(fmaxf(red[0], red[1]), fmaxf(red[2], red[3]));
    float e = __expf(sc - m);
    float ssum = e;
#pragma unroll
    for (int off = 32; off; off >>= 1) ssum += __shfl_xor(ssum, off);
    if ((tid & 63) == 0) red[4 + (tid >> 6)] = ssum;
    __syncthreads();
    ssum = red[4] + red[5] + red[6] + red[7];
    al[tid] = e / ssum;
    __syncthreads();

    int d = tid & 127, half = tid >> 7;
    float acc = 0.f;
    for (int t = half; t < SS; t += 2) acc += al[t] * z[((size_t)b * SS + t) * DD + d];
    pp[half][d] = acc;
    __syncthreads();
    if (tid < 128) pooled[b * 128 + tid] = pp[0][tid] + pp[1][tid];
}

// ---------------------------------------------------------------- routed heads
__global__ __launch_bounds__(128) void head_kernel(const float* __restrict__ pooled,
                                                   const float* __restrict__ reg_w,
                                                   const float* __restrict__ reg_b,
                                                   const float* __restrict__ bin_w,
                                                   const float* __restrict__ bin_b,
                                                   const int* __restrict__ wid,
                                                   float* __restrict__ out) {
    int b = blockIdx.x, tid = threadIdx.x;
    __shared__ float p[128];
    p[tid] = pooled[b * 128 + tid];
    __syncthreads();
    if (tid < 9) {
        int w = wid[b];
        const float* wrow;
        float bias;
        if (tid < 8) { wrow = reg_w + ((size_t)w * 8 + tid) * 128; bias = reg_b[w * 8 + tid]; }
        else         { wrow = bin_w + (size_t)w * 128;             bias = bin_b[w]; }
        float acc = bias;
        for (int k = 0; k < 128; ++k) acc += wrow[k] * p[k];
        if (tid < 8) out[b * 8 + tid] = acc;
        else         out[1024 + b] = acc;
    }
}

// ================================================================ host
extern "C" void kernel_launch(void* const* d_in, const int* in_sizes, int n_in,
                              void* d_out, int out_size, void* d_ws, size_t ws_size,
                              hipStream_t stream) {
    const float* x         = (const float*)d_in[0];
    const float* mask      = (const float*)d_in[1];
    const float* delta     = (const float*)d_in[2];
    const float* gru_w_ih  = (const float*)d_in[3];
    const float* gru_w_hh  = (const float*)d_in[4];
    const float* gru_b_ih  = (const float*)d_in[5];
    const float* gru_b_hh  = (const float*)d_in[6];
    const float* dm_w      = (const float*)d_in[7];
    const float* dm_b      = (const float*)d_in[8];
    const float* in_proj_w = (const float*)d_in[9];
    const float* in_proj_b = (const float*)d_in[10];
    const float* out_proj_w= (const float*)d_in[11];
    const float* out_proj_b= (const float*)d_in[12];
    const float* lin1_w    = (const float*)d_in[13];
    const float* lin1_b    = (const float*)d_in[14];
    const float* lin2_w    = (const float*)d_in[15];
    const float* lin2_b    = (const float*)d_in[16];
    const float* ln1_s     = (const float*)d_in[17];
    const float* ln1_bb    = (const float*)d_in[18];
    const float* ln2_s     = (const float*)d_in[19];
    const float* ln2_bb    = (const float*)d_in[20];
    const float* score_w   = (const float*)d_in[21];
    const float* score_b   = (const float*)d_in[22];
    const float* reg_w     = (const float*)d_in[23];
    const float* reg_b     = (const float*)d_in[24];
    const float* bin_w     = (const float*)d_in[25];
    const float* bin_b     = (const float*)d_in[26];
    const int*   window_id = (const int*)d_in[27];
    float* out = (float*)d_out;

    char* w8 = (char*)d_ws;
    float* z      = (float*)(w8 + 0);            // 16,777,216
    u16*   zb     = (u16*)  (w8 + 16777216);     //  8,388,608
    u16*   hsb    = (u16*)  (w8 + 25165824);     //  4,194,304
    u16*   wb_dm  = (u16*)  (w8 + 29360128);     //     16,384
    u16*   wb_ip  = (u16*)  (w8 + 29376512);     //    196,608
    u16*   wb_op  = (u16*)  (w8 + 29573120);     //     65,536
    u16*   wb_l1  = (u16*)  (w8 + 29638656);     //  1,048,576
    u16*   wb_l2  = (u16*)  (w8 + 30687232);     //  1,048,576
    float* tm     = (float*)(w8 + 31735808);     //    131,072
    float* scores = (float*)(w8 + 31866880);     //    131,072
    float* pooled = (float*)(w8 + 31997952);     //     65,536
    float* xwt    = (float*)(w8 + 32063488);     // 25,165,824 (GRU: xwt fp32 | later: qkvb bf16)
    u16*   qkvb   = (u16*)  (w8 + 32063488);
    u16*   attnob = (u16*)  (w8 + 57229312);     //  8,388,608   (total ~65.6MB)

    cvt_all_kernel<<<580, 256, 0, stream>>>(dm_w, in_proj_w, out_proj_w, lin1_w, lin2_w,
                                            wb_dm, wb_ip, wb_op, wb_l1, wb_l2);

    tm_kernel<<<(BB * SS + 255) / 256, 256, 0, stream>>>(mask, tm);
    xw_kernel<<<2048, 192, 0, stream>>>(x, mask, delta, gru_w_ih, gru_b_ih, xwt);
    gru_scan_kernel<<<8, 256, 0, stream>>>(gru_w_hh, gru_b_hh, xwt, hsb);

    mfma_gemm<3, false><<<dim3(256, 1), 256, 0, stream>>>(
        hsb, wb_dm, dm_b, z, zb, nullptr, nullptr, 32768, 128, 64);

    for (int l = 0; l < LL; ++l) {
        mfma_gemm<2, false><<<dim3(256, 3), 256, 0, stream>>>(
            zb, wb_ip + (size_t)l * 49152, in_proj_b + l * 384, nullptr, qkvb,
            nullptr, nullptr, 32768, 384, 128);
        attn_mfma_kernel<<<BB * NHH, 256, 0, stream>>>(qkvb, tm, attnob);
        mfma_gemm<4, false><<<dim3(256, 1), 256, 0, stream>>>(
            attnob, wb_op + (size_t)l * 16384, out_proj_b + l * 128, z, zb,
            ln1_s + l * 128, ln1_bb + l * 128, 32768, 128, 128);
        ff_fused_kernel<<<256, 256, 0, stream>>>(
            zb, wb_l1 + (size_t)l * 262144, lin1_b + l * 2048,
            wb_l2 + (size_t)l * 262144, lin2_b + l * 128,
            ln2_s + l * 128, ln2_bb + l * 128, z, zb);
    }

    score_kernel<<<BB * SS / 64, 256, 0, stream>>>(z, score_w, score_b, tm, scores);
    pool_kernel<<<BB, 256, 0, stream>>>(z, scores, pooled);
    head_kernel<<<BB, 128, 0, stream>>>(pooled, reg_w, reg_b, bin_w, bin_b, window_id, out);
}

// Round 12
// 544.368 us; speedup vs baseline: 1.2594x; 1.0319x over previous
//
#include <hip/hip_runtime.h>

typedef __attribute__((ext_vector_type(8))) short short8;
typedef __attribute__((ext_vector_type(4))) float f32x4;
typedef unsigned short u16;

#define BB   128
#define SS   256
#define FIN  40
#define HH   64
#define DD   128
#define NHH  4
#define LL   2
#define NEGV (-1e9f)

__device__ __forceinline__ u16 f2b(float f) {
    unsigned u = __float_as_uint(f);
    return (u16)((u + 0x7FFFu + ((u >> 16) & 1u)) >> 16);
}
__device__ __forceinline__ float b2f(u16 u) {
    return __uint_as_float(((unsigned)u) << 16);
}

// ---------------------------------------------------------------- merged fp32 -> bf16 weight convert
__global__ __launch_bounds__(256) void cvt_all_kernel(const float* __restrict__ dm_w,
                                                      const float* __restrict__ ip_w,
                                                      const float* __restrict__ op_w,
                                                      const float* __restrict__ l1_w,
                                                      const float* __restrict__ l2_w,
                                                      u16* __restrict__ o_dm, u16* __restrict__ o_ip,
                                                      u16* __restrict__ o_op, u16* __restrict__ o_l1,
                                                      u16* __restrict__ o_l2) {
    int blk = blockIdx.x;
    const float* s; u16* d; int off;
    if      (blk < 4)   { s = dm_w; d = o_dm; off = blk; }
    else if (blk < 52)  { s = ip_w; d = o_ip; off = blk - 4; }
    else if (blk < 68)  { s = op_w; d = o_op; off = blk - 52; }
    else if (blk < 324) { s = l1_w; d = o_l1; off = blk - 68; }
    else                { s = l2_w; d = o_l2; off = blk - 324; }
    int i = (off * 256 + threadIdx.x) * 8;
    float4 a = *(const float4*)&s[i];
    float4 b = *(const float4*)&s[i + 4];
    short8 o;
    o[0] = (short)f2b(a.x); o[1] = (short)f2b(a.y); o[2] = (short)f2b(a.z); o[3] = (short)f2b(a.w);
    o[4] = (short)f2b(b.x); o[5] = (short)f2b(b.y); o[6] = (short)f2b(b.z); o[7] = (short)f2b(b.w);
    *(short8*)&d[i] = o;
}

// ---------------------------------------------------------------- time mask
__global__ __launch_bounds__(256) void tm_kernel(const float* __restrict__ mask,
                                                 float* __restrict__ tm) {
    int i = blockIdx.x * blockDim.x + threadIdx.x;
    if (i >= BB * SS) return;
    const float* m = mask + (size_t)i * FIN;
    float s = 0.f;
    for (int f = 0; f < FIN; ++f) s += m[f];
    tm[i] = (s > 0.f) ? 1.f : 0.f;
}

// ------------------------------------------------- xwt = concat(x,mask,delta) @ W_ih^T + b_ih
// TRANSPOSED output layout for the GRU: xwt[group 0..7][t 0..255][gatecol 0..191][rb 0..15]
__global__ __launch_bounds__(192) void xw_kernel(const float* __restrict__ x,
                                                 const float* __restrict__ mask,
                                                 const float* __restrict__ delta,
                                                 const float* __restrict__ w_ih,
                                                 const float* __restrict__ b_ih,
                                                 float* __restrict__ xwt) {
    __shared__ float inp[16][120];
    __shared__ float wl[192][21];
    int group = blockIdx.x >> 8;
    int t = blockIdx.x & 255;
    int tid = threadIdx.x;

    for (int idx = tid; idx < 16 * 120; idx += 192) {
        int r = idx / 120, k = idx % 120;
        size_t g = (size_t)(group * 16 + r) * 256 + t;
        float v;
        if (k < 40)      v = x[g * FIN + k];
        else if (k < 80) v = mask[g * FIN + (k - 40)];
        else             v = delta[g * FIN + (k - 80)];
        inp[r][k] = v;
    }

    float acc[16];
#pragma unroll
    for (int r = 0; r < 16; ++r) acc[r] = 0.f;

    for (int kt = 0; kt < 6; ++kt) {
        __syncthreads();
        for (int idx = tid; idx < 192 * 20; idx += 192) {
            int r = idx / 20, k = idx % 20;
            wl[r][k] = w_ih[(size_t)r * 120 + kt * 20 + k];
        }
        __syncthreads();
#pragma unroll
        for (int kk = 0; kk < 20; ++kk) {
            float w = wl[tid][kk];
            int kg = kt * 20 + kk;
#pragma unroll
            for (int r = 0; r < 16; ++r) acc[r] += w * inp[r][kg];
        }
    }
    float bias = b_ih[tid];
    float* o = xwt + ((size_t)(group * 256 + t) * 192 + tid) * 16;
#pragma unroll
    for (int r = 0; r < 16; r += 4) {
        float4 v = {acc[r] + bias, acc[r + 1] + bias, acc[r + 2] + bias, acc[r + 3] + bias};
        *(float4*)&o[r] = v;
    }
}

// ---------------------------------------------------------------- MFMA GRU scan v5
// 8 blocks x 16 batch rows, 8 waves (512 thr). R11 cycle model: step = issue(~680: 24 trans
// x16cyc quarter-rate + VALU) + unhidden latency(~1100) at 1 wave/SIMD. v5 j-SPLITS the gate
// work across wave pairs (jg = w>>2): each wave duplicates the cheap MFMAs but computes only
// 2 h/lane (trans issue halves) and 2 waves/SIMD interleave to fill latency.
__device__ __forceinline__ float gru_gate(float xr, float xz, float xn,
                                          float ar, float az, float an, float hold) {
    float r  = 1.f / (1.f + __expf(-(xr + ar)));
    float zg = 1.f / (1.f + __expf(-(xz + az)));
    float nx = xn + r * an;
    float n  = 2.f / (1.f + __expf(-2.f * nx)) - 1.f;   // tanh
    return (1.f - zg) * n + zg * hold;
}

__global__ __launch_bounds__(512, 1) void gru_scan_kernel(const float* __restrict__ w_hh,
                                                          const float* __restrict__ b_hh,
                                                          const float* __restrict__ xwt,
                                                          u16* __restrict__ hsb) {
    __shared__ __align__(16) u16 hb[2][16 * 64];   // bf16 h A-frag source, slot^(row&7) swizzled
    int b0 = blockIdx.x * 16;
    int tid = threadIdx.x;
    int w = tid >> 6, lane = tid & 63;
    int fr = lane & 15, hi = lane >> 4;
    int cw = w & 3;                      // col-wave: gate col slice
    int jg = w >> 2;                     // j-group: 0 -> j{0,1}, 1 -> j{2,3}

    for (int idx = tid; idx < 1024; idx += 512) hb[0][idx] = 0;

    int c = cw * 16 + fr;                // gate col / h col owned by this lane
    float br_ = b_hh[c], bz_ = b_hh[64 + c], bn_ = b_hh[128 + c];

    // W_hh B-fragments in registers (loop-invariant, 24 VGPR)
    short8 wfr[2], wfz[2], wfn[2];
#pragma unroll
    for (int ks = 0; ks < 2; ++ks) {
        int slot = ks * 4 + hi;
        const float* p0 = w_hh + (size_t)c * 64 + slot * 8;
        const float* p1 = w_hh + (size_t)(64 + c) * 64 + slot * 8;
        const float* p2 = w_hh + (size_t)(128 + c) * 64 + slot * 8;
#pragma unroll
        for (int q = 0; q < 8; ++q) {
            wfr[ks][q] = (short)f2b(p0[q]);
            wfz[ks][q] = (short)f2b(p1[q]);
            wfn[ks][q] = (short)f2b(p2[q]);
        }
    }

    const float* xg = xwt + (size_t)blockIdx.x * (256 * 192 * 16);
    int lo = hi * 4 + jg * 2;            // first of this lane's 2 rows

    float hrA = 0.f, hrB = 0.f;          // h state, exclusive per lane (2 rows)

    int woA = (lo + 0) * 64 + ((((c >> 3) ^ ((lo + 0) & 7))) << 3) + (c & 7);
    int woB = (lo + 1) * 64 + ((((c >> 3) ^ ((lo + 1) & 7))) << 3) + (c & 7);
    size_t hoA = ((size_t)(b0 + lo + 0) * SS) * 64 + c;
    size_t hoB = ((size_t)(b0 + lo + 1) * SS) * 64 + c;

    // depth-2 prefetch (A=t0, B=t1), float2 per gate
    float2 axr = *(const float2*)&xg[((size_t)0 * 192 + c) * 16 + lo];
    float2 axz = *(const float2*)&xg[((size_t)0 * 192 + 64 + c) * 16 + lo];
    float2 axn = *(const float2*)&xg[((size_t)0 * 192 + 128 + c) * 16 + lo];
    float2 bxr = *(const float2*)&xg[((size_t)1 * 192 + c) * 16 + lo];
    float2 bxz = *(const float2*)&xg[((size_t)1 * 192 + 64 + c) * 16 + lo];
    float2 bxn = *(const float2*)&xg[((size_t)1 * 192 + 128 + c) * 16 + lo];
    __syncthreads();   // hb[0] visible

    int cur = 0;
    auto step = [&](float2 xr2, float2 xz2, float2 xn2, int t) {
        f32x4 ar = {br_, br_, br_, br_};
        f32x4 az = {bz_, bz_, bz_, bz_};
        f32x4 an = {bn_, bn_, bn_, bn_};
#pragma unroll
        for (int ks = 0; ks < 2; ++ks) {
            int soff = (((ks << 2) + hi) ^ (fr & 7)) << 3;
            short8 af = *(const short8*)&hb[cur][fr * 64 + soff];
            ar = __builtin_amdgcn_mfma_f32_16x16x32_bf16(af, wfr[ks], ar, 0, 0, 0);
            az = __builtin_amdgcn_mfma_f32_16x16x32_bf16(af, wfz[ks], az, 0, 0, 0);
            an = __builtin_amdgcn_mfma_f32_16x16x32_bf16(af, wfn[ks], an, 0, 0, 0);
        }
        float aR0, aR1, aZ0, aZ1, aN0, aN1;
        if (jg == 0) { aR0 = ar[0]; aR1 = ar[1]; aZ0 = az[0]; aZ1 = az[1]; aN0 = an[0]; aN1 = an[1]; }
        else         { aR0 = ar[2]; aR1 = ar[3]; aZ0 = az[2]; aZ1 = az[3]; aN0 = an[2]; aN1 = an[3]; }
        hrA = gru_gate(xr2.x, xz2.x, xn2.x, aR0, aZ0, aN0, hrA);
        hrB = gru_gate(xr2.y, xz2.y, xn2.y, aR1, aZ1, aN1, hrB);
        u16 v0 = f2b(hrA), v1 = f2b(hrB);
        int nxt = cur ^ 1;
        hb[nxt][woA] = v0; hb[nxt][woB] = v1;      // disjoint rows across wave-pairs
        hsb[hoA + (size_t)t * 64] = v0;
        hsb[hoB + (size_t)t * 64] = v1;
        // LDS-only drain + raw barrier: global prefetch loads stay in flight
        asm volatile("s_waitcnt lgkmcnt(0)\n\ts_barrier" ::: "memory");
        cur = nxt;
    };

    for (int t = 0; t < SS; t += 2) {
        {
            int tp = (t + 2 < SS) ? t + 2 : t;
            float2 nr = *(const float2*)&xg[((size_t)tp * 192 + c) * 16 + lo];
            float2 nz = *(const float2*)&xg[((size_t)tp * 192 + 64 + c) * 16 + lo];
            float2 nn = *(const float2*)&xg[((size_t)tp * 192 + 128 + c) * 16 + lo];
            step(axr, axz, axn, t);
            axr = nr; axz = nz; axn = nn;
        }
        {
            int tp = (t + 3 < SS) ? t + 3 : t + 1;
            float2 nr = *(const float2*)&xg[((size_t)tp * 192 + c) * 16 + lo];
            float2 nz = *(const float2*)&xg[((size_t)tp * 192 + 64 + c) * 16 + lo];
            float2 nn = *(const float2*)&xg[((size_t)tp * 192 + 128 + c) * 16 + lo];
            step(bxr, bxz, bxn, t + 1);
            bxr = nr; bxz = nz; bxn = nn;
        }
    }
}

// ---------------------------------------------------------------- bf16 MFMA GEMM (BK=64, swizzled)
__device__ __forceinline__ void gl_lds16(const void* g, void* s) {
    __builtin_amdgcn_global_load_lds(
        (const __attribute__((address_space(1))) void*)g,
        (__attribute__((address_space(3))) void*)s, 16, 0, 0);
}

template <int MODE, bool RELU>
__global__ __launch_bounds__(256, 2) void mfma_gemm(const u16* __restrict__ A,
                                                    const u16* __restrict__ W,
                                                    const float* __restrict__ bias,
                                                    float* __restrict__ C,
                                                    u16* __restrict__ Cb,
                                                    const float* __restrict__ lns,
                                                    const float* __restrict__ lnb,
                                                    int M, int N, int K) {
    __shared__ __align__(16) u16 Al[128 * 64];
    __shared__ __align__(16) u16 Bl[128 * 64];
    __shared__ float lred[2][2][128];
    int bm = blockIdx.x, bn = blockIdx.y;
    int tid = threadIdx.x;
    int w = tid >> 6, lane = tid & 63;
    int wrow = (w >> 1) * 64, wcol = (w & 1) * 64;
    int fr = lane & 15, hi = lane >> 4;
    int rl = lane >> 3;
    int sl = lane & 7;
    int ssl = sl ^ rl;

    const u16* Ag = A + ((size_t)bm * 128) * K + ssl * 8;
    const u16* Wg = W + ((size_t)bn * 128) * K + ssl * 8;

    f32x4 acc[4][4];
#pragma unroll
    for (int i = 0; i < 4; ++i)
#pragma unroll
        for (int jj = 0; jj < 4; ++jj) acc[i][jj] = (f32x4){0.f, 0.f, 0.f, 0.f};

    int ar[4], br[4];
#pragma unroll
    for (int m = 0; m < 4; ++m) {
        ar[m] = (wrow + m * 16 + fr) * 64;
        br[m] = (wcol + m * 16 + fr) * 64;
    }
    int swz = (fr & 7);

    for (int kt = 0; kt < K; kt += 64) {
        __syncthreads();
#pragma unroll
        for (int i = 0; i < 4; ++i) {
            int c = w * 4 + i;
            int row = c * 8 + rl;
            gl_lds16(Ag + (size_t)row * K + kt, &Al[c * 512]);
            gl_lds16(Wg + (size_t)row * K + kt, &Bl[c * 512]);
        }
        __syncthreads();
#pragma unroll
        for (int kk = 0; kk < 2; ++kk) {
            short8 a[4], bq[4];
            int soff = (((kk << 2) + hi) ^ swz) << 3;
#pragma unroll
            for (int m = 0; m < 4; ++m)
                a[m] = *(const short8*)&Al[ar[m] + soff];
#pragma unroll
            for (int n = 0; n < 4; ++n)
                bq[n] = *(const short8*)&Bl[br[n] + soff];
#pragma unroll
            for (int m = 0; m < 4; ++m)
#pragma unroll
                for (int n = 0; n < 4; ++n)
                    acc[m][n] = __builtin_amdgcn_mfma_f32_16x16x32_bf16(a[m], bq[n], acc[m][n], 0, 0, 0);
        }
    }

    float bv[4];
#pragma unroll
    for (int n = 0; n < 4; ++n) bv[n] = bias[bn * 128 + wcol + n * 16 + fr];

    if (MODE == 4) {
        float v[4][4][4];
#pragma unroll
        for (int m = 0; m < 4; ++m)
#pragma unroll
            for (int j = 0; j < 4; ++j) {
                int row = bm * 128 + wrow + m * 16 + hi * 4 + j;
#pragma unroll
                for (int n = 0; n < 4; ++n)
                    v[m][n][j] = acc[m][n][j] + bv[n] + C[(size_t)row * 128 + wcol + n * 16 + fr];
            }
#pragma unroll
        for (int m = 0; m < 4; ++m)
#pragma unroll
            for (int j = 0; j < 4; ++j) {
                float s = v[m][0][j] + v[m][1][j] + v[m][2][j] + v[m][3][j];
                float q = v[m][0][j]*v[m][0][j] + v[m][1][j]*v[m][1][j]
                        + v[m][2][j]*v[m][2][j] + v[m][3][j]*v[m][3][j];
#pragma unroll
                for (int off = 1; off <= 8; off <<= 1) {
                    s += __shfl_xor(s, off);
                    q += __shfl_xor(q, off);
                }
                if (fr == 0) {
                    int lrow = wrow + m * 16 + hi * 4 + j;
                    lred[0][w & 1][lrow] = s;
                    lred[1][w & 1][lrow] = q;
                }
            }
        __syncthreads();
        float sv[4], bb[4];
#pragma unroll
        for (int n = 0; n < 4; ++n) {
            sv[n] = lns[wcol + n * 16 + fr];
            bb[n] = lnb[wcol + n * 16 + fr];
        }
#pragma unroll
        for (int m = 0; m < 4; ++m)
#pragma unroll
            for (int j = 0; j < 4; ++j) {
                int lrow = wrow + m * 16 + hi * 4 + j;
                float mean = (lred[0][0][lrow] + lred[0][1][lrow]) * (1.f / 128.f);
                float msq  = (lred[1][0][lrow] + lred[1][1][lrow]) * (1.f / 128.f);
                float rstd = rsqrtf(msq - mean * mean + 1e-5f);
                int row = bm * 128 + lrow;
#pragma unroll
                for (int n = 0; n < 4; ++n) {
                    int col = wcol + n * 16 + fr;
                    float o = (v[m][n][j] - mean) * rstd * sv[n] + bb[n];
                    C[(size_t)row * 128 + col] = o;
                    Cb[(size_t)row * 128 + col] = f2b(o);
                }
            }
    } else {
#pragma unroll
        for (int m = 0; m < 4; ++m) {
#pragma unroll
            for (int j = 0; j < 4; ++j) {
                int row = bm * 128 + wrow + m * 16 + hi * 4 + j;
#pragma unroll
                for (int n = 0; n < 4; ++n) {
                    int col = bn * 128 + wcol + n * 16 + fr;
                    float vv = acc[m][n][j] + bv[n];
                    if (RELU) vv = fmaxf(vv, 0.f);
                    if (MODE & 1) C[(size_t)row * N + col] = vv;
                    if (MODE & 2) Cb[(size_t)row * N + col] = f2b(vv);
                }
            }
        }
    }
}

// ---------------------------------------------------------------- fused FF (unchanged)
__global__ __launch_bounds__(256, 1) void ff_fused_kernel(const u16* __restrict__ zbin,
                                                          const u16* __restrict__ w1,
                                                          const float* __restrict__ b1,
                                                          const u16* __restrict__ w2,
                                                          const float* __restrict__ b2,
                                                          const float* __restrict__ lns,
                                                          const float* __restrict__ lnb,
                                                          float* __restrict__ z,
                                                          u16* __restrict__ zbout) {
    __shared__ __align__(16) u16 ZB[2][128 * 64];
    __shared__ __align__(16) u16 W1C[2][128 * 64];
    __shared__ __align__(16) u16 W2C[2][128 * 64];
    __shared__ __align__(16) u16 A1[2][128 * 64];
    __shared__ float lred[2][2][128];
    int bm = blockIdx.x;
    int tid = threadIdx.x;
    int w = tid >> 6, lane = tid & 63;
    int wrow = (w >> 1) * 64, wcol = (w & 1) * 64;
    int fr = lane & 15, hi = lane >> 4;
    int rl = lane >> 3, ssl = (lane & 7) ^ rl;
    int swz = fr & 7;
    int xh = wrow >> 6;

#pragma unroll
    for (int hk = 0; hk < 2; ++hk)
#pragma unroll
        for (int i = 0; i < 4; ++i) {
            int ch = w * 4 + i, row = ch * 8 + rl;
            gl_lds16(zbin + ((size_t)(bm * 128 + row)) * 128 + hk * 64 + ssl * 8, &ZB[hk][ch * 512]);
        }

    f32x4 acc2[4][4];
#pragma unroll
    for (int m = 0; m < 4; ++m)
#pragma unroll
        for (int n = 0; n < 4; ++n) acc2[m][n] = (f32x4){0.f, 0.f, 0.f, 0.f};

    for (int ci = 0; ci < 16; ++ci) {
#pragma unroll
        for (int hk = 0; hk < 2; ++hk)
#pragma unroll
            for (int i = 0; i < 4; ++i) {
                int ch = w * 4 + i, row = ch * 8 + rl;
                gl_lds16(w1 + ((size_t)(ci * 128 + row)) * 128 + hk * 64 + ssl * 8, &W1C[hk][ch * 512]);
                gl_lds16(w2 + ((size_t)row) * 2048 + ci * 128 + hk * 64 + ssl * 8, &W2C[hk][ch * 512]);
            }
        __syncthreads();

        f32x4 acc1[4][4];
#pragma unroll
        for (int m = 0; m < 4; ++m)
#pragma unroll
            for (int n = 0; n < 4; ++n) acc1[m][n] = (f32x4){0.f, 0.f, 0.f, 0.f};
#pragma unroll
        for (int ks = 0; ks < 4; ++ks) {
            int hk = ks >> 1;
            int soff = ((((ks & 1) << 2) + hi) ^ swz) << 3;
            short8 a[4], b[4];
#pragma unroll
            for (int m = 0; m < 4; ++m)
                a[m] = *(const short8*)&W1C[hk][(wrow + m * 16 + fr) * 64 + soff];
#pragma unroll
            for (int n = 0; n < 4; ++n)
                b[n] = *(const short8*)&ZB[hk][(wcol + n * 16 + fr) * 64 + soff];
#pragma unroll
            for (int m = 0; m < 4; ++m)
#pragma unroll
                for (int n = 0; n < 4; ++n)
                    acc1[m][n] = __builtin_amdgcn_mfma_f32_16x16x32_bf16(a[m], b[n], acc1[m][n], 0, 0, 0);
        }
#pragma unroll
        for (int m = 0; m < 4; ++m) {
            int x0 = wrow + m * 16 + hi * 4;
            float4 bb = *(const float4*)&b1[ci * 128 + x0];
            int slot = (x0 & 63) >> 3;
            int wadd = x0 & 7;
#pragma unroll
            for (int n = 0; n < 4; ++n) {
                int r = wcol + n * 16 + fr;
                float v0 = fmaxf(acc1[m][n][0] + bb.x, 0.f);
                float v1 = fmaxf(acc1[m][n][1] + bb.y, 0.f);
                float v2 = fmaxf(acc1[m][n][2] + bb.z, 0.f);
                float v3 = fmaxf(acc1[m][n][3] + bb.w, 0.f);
                uint2 pk;
                pk.x = (unsigned)f2b(v0) | ((unsigned)f2b(v1) << 16);
                pk.y = (unsigned)f2b(v2) | ((unsigned)f2b(v3) << 16);
                *(uint2*)&A1[xh][r * 64 + ((slot ^ (r & 7)) << 3) + wadd] = pk;
            }
        }
        __syncthreads();

#pragma unroll
        for (int ks = 0; ks < 4; ++ks) {
            int hk = ks >> 1;
            int soff = ((((ks & 1) << 2) + hi) ^ swz) << 3;
            short8 a[4], b[4];
#pragma unroll
            for (int m = 0; m < 4; ++m)
                a[m] = *(const short8*)&W2C[hk][(wrow + m * 16 + fr) * 64 + soff];
#pragma unroll
            for (int n = 0; n < 4; ++n)
                b[n] = *(const short8*)&A1[hk][(wcol + n * 16 + fr) * 64 + soff];
#pragma unroll
            for (int m = 0; m < 4; ++m)
#pragma unroll
                for (int n = 0; n < 4; ++n)
                    acc2[m][n] = __builtin_amdgcn_mfma_f32_16x16x32_bf16(a[m], b[n], acc2[m][n], 0, 0, 0);
        }
        __syncthreads();
    }

    float vv[4][4][4];
#pragma unroll
    for (int m = 0; m < 4; ++m) {
        int x0 = wrow + m * 16 + hi * 4;
        float4 bb = *(const float4*)&b2[x0];
#pragma unroll
        for (int n = 0; n < 4; ++n) {
            int y = wcol + n * 16 + fr;
            float4 zo = *(const float4*)&z[((size_t)(bm * 128 + y)) * 128 + x0];
            vv[m][n][0] = acc2[m][n][0] + bb.x + zo.x;
            vv[m][n][1] = acc2[m][n][1] + bb.y + zo.y;
            vv[m][n][2] = acc2[m][n][2] + bb.z + zo.z;
            vv[m][n][3] = acc2[m][n][3] + bb.w + zo.w;
        }
    }
#pragma unroll
    for (int n = 0; n < 4; ++n) {
        float s = 0.f, q = 0.f;
#pragma unroll
        for (int m = 0; m < 4; ++m)
#pragma unroll
            for (int j = 0; j < 4; ++j) { float v = vv[m][n][j]; s += v; q += v * v; }
        s += __shfl_xor(s, 16); s += __shfl_xor(s, 32);
        q += __shfl_xor(q, 16); q += __shfl_xor(q, 32);
        if (hi == 0) {
            int y = wcol + n * 16 + fr;
            lred[0][xh][y] = s;
            lred[1][xh][y] = q;
        }
    }
    __syncthreads();
#pragma unroll
    for (int n = 0; n < 4; ++n) {
        int y = wcol + n * 16 + fr;
        float mean = (lred[0][0][y] + lred[0][1][y]) * (1.f / 128.f);
        float msq  = (lred[1][0][y] + lred[1][1][y]) * (1.f / 128.f);
        float rstd = rsqrtf(msq - mean * mean + 1e-5f);
#pragma unroll
        for (int m = 0; m < 4; ++m) {
            int x0 = wrow + m * 16 + hi * 4;
            float4 sv = *(const float4*)&lns[x0];
            float4 bv = *(const float4*)&lnb[x0];
            float o0 = (vv[m][n][0] - mean) * rstd * sv.x + bv.x;
            float o1 = (vv[m][n][1] - mean) * rstd * sv.y + bv.y;
            float o2 = (vv[m][n][2] - mean) * rstd * sv.z + bv.z;
            float o3 = (vv[m][n][3] - mean) * rstd * sv.w + bv.w;
            size_t zoff = ((size_t)(bm * 128 + y)) * 128 + x0;
            *(float4*)&z[zoff] = (float4){o0, o1, o2, o3};
            uint2 pk;
            pk.x = (unsigned)f2b(o0) | ((unsigned)f2b(o1) << 16);
            pk.y = (unsigned)f2b(o2) | ((unsigned)f2b(o3) << 16);
            *(uint2*)&zbout[zoff] = pk;
        }
    }
}

// ---------------------------------------------------------------- MFMA attention (unchanged)
__global__ __launch_bounds__(256) void attn_mfma_kernel(const u16* __restrict__ qkv,
                                                        const float* __restrict__ tm,
                                                        u16* __restrict__ attno) {
    __shared__ __align__(16) u16 Kl[256 * 40];
    __shared__ __align__(16) u16 Vt[32 * 264];
    __shared__ __align__(16) u16 Pl[4][64 * 72];
    __shared__ float tmb[256];
    int bh = blockIdx.x;
    int b = bh >> 2, hd = bh & 3;
    int tid = threadIdx.x;
    int w = tid >> 6, lane = tid & 63;
    int fr = lane & 15, hi = lane >> 4;
    const u16* base = qkv + (size_t)b * SS * 384 + hd * 32;

    for (int idx = tid; idx < 1024; idx += 256) {
        int r = idx >> 2, s = idx & 3;
        short8 v = *(const short8*)(base + (size_t)r * 384 + 128 + s * 8);
        *(short8*)&Kl[r * 40 + s * 8] = v;
    }
    for (int idx = tid; idx < 1024; idx += 256) {
        int r = idx >> 2, s = idx & 3;
        short8 v = *(const short8*)(base + (size_t)r * 384 + 256 + s * 8);
#pragma unroll
        for (int q = 0; q < 8; ++q) Vt[(s * 8 + q) * 264 + r] = (u16)v[q];
    }
    tmb[tid] = (tm[b * SS + tid] > 0.f) ? 0.f : NEGV;

    int q0 = w * 64;
    short8 qf[4];
#pragma unroll
    for (int m = 0; m < 4; ++m)
        qf[m] = *(const short8*)(base + (size_t)(q0 + m * 16 + fr) * 384 + hi * 8);
    __syncthreads();

    const float scale = 0.17677669529663687f;
    f32x4 accO[4][2];
#pragma unroll
    for (int m = 0; m < 4; ++m) {
        accO[m][0] = (f32x4){0.f, 0.f, 0.f, 0.f};
        accO[m][1] = (f32x4){0.f, 0.f, 0.f, 0.f};
    }
    float den[4][4];
#pragma unroll
    for (int m = 0; m < 4; ++m)
#pragma unroll
        for (int j = 0; j < 4; ++j) den[m][j] = 0.f;

    u16* pw = &Pl[w][0];

    for (int kt = 0; kt < 4; ++kt) {
        f32x4 accS[4][4];
#pragma unroll
        for (int m = 0; m < 4; ++m)
#pragma unroll
            for (int n = 0; n < 4; ++n) accS[m][n] = (f32x4){0.f, 0.f, 0.f, 0.f};
        short8 kf[4];
#pragma unroll
        for (int n = 0; n < 4; ++n)
            kf[n] = *(const short8*)&Kl[(kt * 64 + n * 16 + fr) * 40 + hi * 8];
#pragma unroll
        for (int m = 0; m < 4; ++m)
#pragma unroll
            for (int n = 0; n < 4; ++n)
                accS[m][n] = __builtin_amdgcn_mfma_f32_16x16x32_bf16(qf[m], kf[n], accS[m][n], 0, 0, 0);

        float bias[4];
#pragma unroll
        for (int n = 0; n < 4; ++n) bias[n] = tmb[kt * 64 + n * 16 + fr];

#pragma unroll
        for (int m = 0; m < 4; ++m) {
            float rs0 = 0.f, rs1 = 0.f, rs2 = 0.f, rs3 = 0.f;
#pragma unroll
            for (int n = 0; n < 4; ++n) {
                float p0 = __expf(accS[m][n][0] * scale + bias[n]);
                float p1 = __expf(accS[m][n][1] * scale + bias[n]);
                float p2 = __expf(accS[m][n][2] * scale + bias[n]);
                float p3 = __expf(accS[m][n][3] * scale + bias[n]);
                rs0 += p0; rs1 += p1; rs2 += p2; rs3 += p3;
                int cb = n * 16 + fr;
                pw[(m * 16 + hi * 4 + 0) * 72 + cb] = f2b(p0);
                pw[(m * 16 + hi * 4 + 1) * 72 + cb] = f2b(p1);
                pw[(m * 16 + hi * 4 + 2) * 72 + cb] = f2b(p2);
                pw[(m * 16 + hi * 4 + 3) * 72 + cb] = f2b(p3);
            }
#pragma unroll
            for (int off = 1; off <= 8; off <<= 1) {
                rs0 += __shfl_xor(rs0, off);
                rs1 += __shfl_xor(rs1, off);
                rs2 += __shfl_xor(rs2, off);
                rs3 += __shfl_xor(rs3, off);
            }
            den[m][0] += rs0; den[m][1] += rs1; den[m][2] += rs2; den[m][3] += rs3;
        }
        asm volatile("s_waitcnt lgkmcnt(0)" ::: "memory");

#pragma unroll
        for (int ks = 0; ks < 2; ++ks) {
            short8 pf[4], vf[2];
#pragma unroll
            for (int m = 0; m < 4; ++m)
                pf[m] = *(const short8*)&pw[(m * 16 + fr) * 72 + ks * 32 + hi * 8];
#pragma unroll
            for (int nd = 0; nd < 2; ++nd)
                vf[nd] = *(const short8*)&Vt[(nd * 16 + fr) * 264 + kt * 64 + ks * 32 + hi * 8];
#pragma unroll
            for (int m = 0; m < 4; ++m)
#pragma unroll
                for (int nd = 0; nd < 2; ++nd)
                    accO[m][nd] = __builtin_amdgcn_mfma_f32_16x16x32_bf16(pf[m], vf[nd], accO[m][nd], 0, 0, 0);
        }
    }

    u16* orow = attno + (size_t)(b * SS + q0) * DD + hd * 32;
#pragma unroll
    for (int m = 0; m < 4; ++m)
#pragma unroll
        for (int j = 0; j < 4; ++j) {
            float inv = 1.f / den[m][j];
            int qr = m * 16 + hi * 4 + j;
            orow[(size_t)qr * DD + fr]      = f2b(accO[m][0][j] * inv);
            orow[(size_t)qr * DD + 16 + fr] = f2b(accO[m][1][j] * inv);
        }
}

// ---------------------------------------------------------------- fused score + softmax-pool + routed heads
// one block per batch row b; replaces score/pool/head (3 dispatches -> 1, no scores/pooled globals)
__global__ __launch_bounds__(256) void pool_all_kernel(const float* __restrict__ z,
                                                       const float* __restrict__ score_w,
                                                       const float* __restrict__ score_b,
                                                       const float* __restrict__ tm,
                                                       const float* __restrict__ reg_w,
                                                       const float* __restrict__ reg_b,
                                                       const float* __restrict__ bin_w,
                                                       const float* __restrict__ bin_b,
                                                       const int* __restrict__ wid,
                                                       float* __restrict__ out) {
    int b = blockIdx.x;
    int tid = threadIdx.x;
    __shared__ float sw[128];
    __shared__ float al[SS];
    __shared__ float red[8];
    __shared__ float pp[2][128];
    __shared__ float p[128];

    if (tid < 128) sw[tid] = score_w[tid];
    __syncthreads();

    // score for row tid
    const float* zr = z + ((size_t)b * SS + tid) * DD;
    float acc = 0.f;
#pragma unroll
    for (int j = 0; j < 128; j += 4) {
        float4 a = *(const float4*)&zr[j];
        float4 wv = *(const float4*)&sw[j];
        acc += a.x * wv.x + a.y * wv.y + a.z * wv.z + a.w * wv.w;
    }
    float sc = acc + score_b[0];
    sc = (tm[b * SS + tid] > 0.f) ? sc : NEGV;

    // softmax over 256
    float m = sc;
#pragma unroll
    for (int off = 32; off; off >>= 1) m = fmaxf(m, __shfl_xor(m, off));
    if ((tid & 63) == 0) red[tid >> 6] = m;
    __syncthreads();
    m = fmaxf(fmaxf(red[0], red[1]), fmaxf(red[2], red[3]));
    float e = __expf(sc - m);
    float ssum = e;
#pragma unroll
    for (int off = 32; off; off >>= 1) ssum += __shfl_xor(ssum, off);
    if ((tid & 63) == 0) red[4 + (tid >> 6)] = ssum;
    __syncthreads();
    ssum = red[4] + red[5] + red[6] + red[7];
    al[tid] = e / ssum;
    __syncthreads();

    // pooled
    int d = tid & 127, half = tid >> 7;
    float pa = 0.f;
    for (int t = half; t < SS; t += 2) pa += al[t] * z[((size_t)b * SS + t) * DD + d];
    pp[half][d] = pa;
    __syncthreads();
    if (tid < 128) p[tid] = pp[0][tid] + pp[1][tid];
    __syncthreads();

    // routed heads
    if (tid < 9) {
        int wi = wid[b];
        const float* wrow;
        float bias;
        if (tid < 8) { wrow = reg_w + ((size_t)wi * 8 + tid) * 128; bias = reg_b[wi * 8 + tid]; }
        else         { wrow = bin_w + (size_t)wi * 128;             bias = bin_b[wi]; }
        float hacc = bias;
        for (int k = 0; k < 128; ++k) hacc += wrow[k] * p[k];
        if (tid < 8) out[b * 8 + tid] = hacc;
        else         out[1024 + b] = hacc;
    }
}

// ================================================================ host
extern "C" void kernel_launch(void* const* d_in, const int* in_sizes, int n_in,
                              void* d_out, int out_size, void* d_ws, size_t ws_size,
                              hipStream_t stream) {
    const float* x         = (const float*)d_in[0];
    const float* mask      = (const float*)d_in[1];
    const float* delta     = (const float*)d_in[2];
    const float* gru_w_ih  = (const float*)d_in[3];
    const float* gru_w_hh  = (const float*)d_in[4];
    const float* gru_b_ih  = (const float*)d_in[5];
    const float* gru_b_hh  = (const float*)d_in[6];
    const float* dm_w      = (const float*)d_in[7];
    const float* dm_b      = (const float*)d_in[8];
    const float* in_proj_w = (const float*)d_in[9];
    const float* in_proj_b = (const float*)d_in[10];
    const float* out_proj_w= (const float*)d_in[11];
    const float* out_proj_b= (const float*)d_in[12];
    const float* lin1_w    = (const float*)d_in[13];
    const float* lin1_b    = (const float*)d_in[14];
    const float* lin2_w    = (const float*)d_in[15];
    const float* lin2_b    = (const float*)d_in[16];
    const float* ln1_s     = (const float*)d_in[17];
    const float* ln1_bb    = (const float*)d_in[18];
    const float* ln2_s     = (const float*)d_in[19];
    const float* ln2_bb    = (const float*)d_in[20];
    const float* score_w   = (const float*)d_in[21];
    const float* score_b   = (const float*)d_in[22];
    const float* reg_w     = (const float*)d_in[23];
    const float* reg_b     = (const float*)d_in[24];
    const float* bin_w     = (const float*)d_in[25];
    const float* bin_b     = (const float*)d_in[26];
    const int*   window_id = (const int*)d_in[27];
    float* out = (float*)d_out;

    char* w8 = (char*)d_ws;
    float* z      = (float*)(w8 + 0);            // 16,777,216
    u16*   zb     = (u16*)  (w8 + 16777216);     //  8,388,608
    u16*   hsb    = (u16*)  (w8 + 25165824);     //  4,194,304
    u16*   wb_dm  = (u16*)  (w8 + 29360128);     //     16,384
    u16*   wb_ip  = (u16*)  (w8 + 29376512);     //    196,608
    u16*   wb_op  = (u16*)  (w8 + 29573120);     //     65,536
    u16*   wb_l1  = (u16*)  (w8 + 29638656);     //  1,048,576
    u16*   wb_l2  = (u16*)  (w8 + 30687232);     //  1,048,576
    float* tm     = (float*)(w8 + 31735808);     //    131,072
    float* xwt    = (float*)(w8 + 32063488);     // 25,165,824 (GRU: xwt fp32 | later: qkvb bf16)
    u16*   qkvb   = (u16*)  (w8 + 32063488);
    u16*   attnob = (u16*)  (w8 + 57229312);     //  8,388,608   (total ~65.6MB)

    cvt_all_kernel<<<580, 256, 0, stream>>>(dm_w, in_proj_w, out_proj_w, lin1_w, lin2_w,
                                            wb_dm, wb_ip, wb_op, wb_l1, wb_l2);

    tm_kernel<<<(BB * SS + 255) / 256, 256, 0, stream>>>(mask, tm);
    xw_kernel<<<2048, 192, 0, stream>>>(x, mask, delta, gru_w_ih, gru_b_ih, xwt);
    gru_scan_kernel<<<8, 512, 0, stream>>>(gru_w_hh, gru_b_hh, xwt, hsb);

    mfma_gemm<3, false><<<dim3(256, 1), 256, 0, stream>>>(
        hsb, wb_dm, dm_b, z, zb, nullptr, nullptr, 32768, 128, 64);

    for (int l = 0; l < LL; ++l) {
        mfma_gemm<2, false><<<dim3(256, 3), 256, 0, stream>>>(
            zb, wb_ip + (size_t)l * 49152, in_proj_b + l * 384, nullptr, qkvb,
            nullptr, nullptr, 32768, 384, 128);
        attn_mfma_kernel<<<BB * NHH, 256, 0, stream>>>(qkvb, tm, attnob);
        mfma_gemm<4, false><<<dim3(256, 1), 256, 0, stream>>>(
            attnob, wb_op + (size_t)l * 16384, out_proj_b + l * 128, z, zb,
            ln1_s + l * 128, ln1_bb + l * 128, 32768, 128, 128);
        ff_fused_kernel<<<256, 256, 0, stream>>>(
            zb, wb_l1 + (size_t)l * 262144, lin1_b + l * 2048,
            wb_l2 + (size_t)l * 262144, lin2_b + l * 128,
            ln2_s + l * 128, ln2_bb + l * 128, z, zb);
    }

    pool_all_kernel<<<BB, 256, 0, stream>>>(z, score_w, score_b, tm,
                                            reg_w, reg_b, bin_w, bin_b, window_id, out);
}

// Round 13
// 503.003 us; speedup vs baseline: 1.3630x; 1.0822x over previous
//
#include <hip/hip_runtime.h>

typedef __attribute__((ext_vector_type(8))) short short8;
typedef __attribute__((ext_vector_type(4))) float f32x4;
typedef unsigned short u16;

#define BB   128
#define SS   256
#define FIN  40
#define HH   64
#define DD   128
#define NHH  4
#define LL   2
#define NEGV (-1e9f)

__device__ __forceinline__ u16 f2b(float f) {
    unsigned u = __float_as_uint(f);
    return (u16)((u + 0x7FFFu + ((u >> 16) & 1u)) >> 16);
}
__device__ __forceinline__ float b2f(u16 u) {
    return __uint_as_float(((unsigned)u) << 16);
}

// ---------------------------------------------------------------- merged fp32 -> bf16 weight convert
__global__ __launch_bounds__(256) void cvt_all_kernel(const float* __restrict__ dm_w,
                                                      const float* __restrict__ ip_w,
                                                      const float* __restrict__ op_w,
                                                      const float* __restrict__ l1_w,
                                                      const float* __restrict__ l2_w,
                                                      u16* __restrict__ o_dm, u16* __restrict__ o_ip,
                                                      u16* __restrict__ o_op, u16* __restrict__ o_l1,
                                                      u16* __restrict__ o_l2) {
    int blk = blockIdx.x;
    const float* s; u16* d; int off;
    if      (blk < 4)   { s = dm_w; d = o_dm; off = blk; }
    else if (blk < 52)  { s = ip_w; d = o_ip; off = blk - 4; }
    else if (blk < 68)  { s = op_w; d = o_op; off = blk - 52; }
    else if (blk < 324) { s = l1_w; d = o_l1; off = blk - 68; }
    else                { s = l2_w; d = o_l2; off = blk - 324; }
    int i = (off * 256 + threadIdx.x) * 8;
    float4 a = *(const float4*)&s[i];
    float4 b = *(const float4*)&s[i + 4];
    short8 o;
    o[0] = (short)f2b(a.x); o[1] = (short)f2b(a.y); o[2] = (short)f2b(a.z); o[3] = (short)f2b(a.w);
    o[4] = (short)f2b(b.x); o[5] = (short)f2b(b.y); o[6] = (short)f2b(b.z); o[7] = (short)f2b(b.w);
    *(short8*)&d[i] = o;
}

// ---------------------------------------------------------------- time mask
__global__ __launch_bounds__(256) void tm_kernel(const float* __restrict__ mask,
                                                 float* __restrict__ tm) {
    int i = blockIdx.x * blockDim.x + threadIdx.x;
    if (i >= BB * SS) return;
    const float* m = mask + (size_t)i * FIN;
    float s = 0.f;
    for (int f = 0; f < FIN; ++f) s += m[f];
    tm[i] = (s > 0.f) ? 1.f : 0.f;
}

// ------------------------------------------------- xwt = concat(x,mask,delta) @ W_ih^T + b_ih
// TRANSPOSED output layout for the GRU: xwt[group 0..7][t 0..255][gatecol 0..191][rb 0..15]
__global__ __launch_bounds__(192) void xw_kernel(const float* __restrict__ x,
                                                 const float* __restrict__ mask,
                                                 const float* __restrict__ delta,
                                                 const float* __restrict__ w_ih,
                                                 const float* __restrict__ b_ih,
                                                 float* __restrict__ xwt) {
    __shared__ float inp[16][120];
    __shared__ float wl[192][21];
    int group = blockIdx.x >> 8;
    int t = blockIdx.x & 255;
    int tid = threadIdx.x;

    for (int idx = tid; idx < 16 * 120; idx += 192) {
        int r = idx / 120, k = idx % 120;
        size_t g = (size_t)(group * 16 + r) * 256 + t;
        float v;
        if (k < 40)      v = x[g * FIN + k];
        else if (k < 80) v = mask[g * FIN + (k - 40)];
        else             v = delta[g * FIN + (k - 80)];
        inp[r][k] = v;
    }

    float acc[16];
#pragma unroll
    for (int r = 0; r < 16; ++r) acc[r] = 0.f;

    for (int kt = 0; kt < 6; ++kt) {
        __syncthreads();
        for (int idx = tid; idx < 192 * 20; idx += 192) {
            int r = idx / 20, k = idx % 20;
            wl[r][k] = w_ih[(size_t)r * 120 + kt * 20 + k];
        }
        __syncthreads();
#pragma unroll
        for (int kk = 0; kk < 20; ++kk) {
            float w = wl[tid][kk];
            int kg = kt * 20 + kk;
#pragma unroll
            for (int r = 0; r < 16; ++r) acc[r] += w * inp[r][kg];
        }
    }
    float bias = b_ih[tid];
    float* o = xwt + ((size_t)(group * 256 + t) * 192 + tid) * 16;
#pragma unroll
    for (int r = 0; r < 16; r += 4) {
        float4 v = {acc[r] + bias, acc[r + 1] + bias, acc[r + 2] + bias, acc[r + 3] + bias};
        *(float4*)&o[r] = v;
    }
}

// ---------------------------------------------------------------- MFMA GRU scan v6
// 8 blocks x 16 batch rows, 8 waves. v5 (j-split) was NULL -> per-step cost is not issue-bound.
// v6 removes the two remaining VMEM suspects from the step loop:
// (1) hsb stores: staged in LDS hstage[8][16*64], flushed every 8 steps with coalesced
//     dwordx4 stores (64x fewer store instrs, no store-queue backpressure in the loop);
// (2) depth-4 xw prefetch (static-indexed via full unroll): loads issued ~4 steps (>2000cyc)
//     ahead of use, covering HBM latency even for short steps.
__device__ __forceinline__ float gru_gate(float xr, float xz, float xn,
                                          float ar, float az, float an, float hold) {
    float r  = 1.f / (1.f + __expf(-(xr + ar)));
    float zg = 1.f / (1.f + __expf(-(xz + az)));
    float nx = xn + r * an;
    float n  = 2.f / (1.f + __expf(-2.f * nx)) - 1.f;   // tanh
    return (1.f - zg) * n + zg * hold;
}

__global__ __launch_bounds__(512, 1) void gru_scan_kernel(const float* __restrict__ w_hh,
                                                          const float* __restrict__ b_hh,
                                                          const float* __restrict__ xwt,
                                                          u16* __restrict__ hsb) {
    __shared__ __align__(16) u16 hb[2][16 * 64];       // bf16 h A-frag source (swizzled)
    __shared__ __align__(16) u16 hstage[8][16 * 64];   // 8-step hs staging (linear), 16KB
    int b0 = blockIdx.x * 16;
    int tid = threadIdx.x;
    int w = tid >> 6, lane = tid & 63;
    int fr = lane & 15, hi = lane >> 4;
    int cw = w & 3;                      // col-wave: gate col slice
    int jg = w >> 2;                     // j-group: 0 -> j{0,1}, 1 -> j{2,3}

    for (int idx = tid; idx < 1024; idx += 512) hb[0][idx] = 0;

    int c = cw * 16 + fr;                // gate col / h col owned by this lane
    float br_ = b_hh[c], bz_ = b_hh[64 + c], bn_ = b_hh[128 + c];

    // W_hh B-fragments in registers (loop-invariant, 24 VGPR)
    short8 wfr[2], wfz[2], wfn[2];
#pragma unroll
    for (int ks = 0; ks < 2; ++ks) {
        int slot = ks * 4 + hi;
        const float* p0 = w_hh + (size_t)c * 64 + slot * 8;
        const float* p1 = w_hh + (size_t)(64 + c) * 64 + slot * 8;
        const float* p2 = w_hh + (size_t)(128 + c) * 64 + slot * 8;
#pragma unroll
        for (int q = 0; q < 8; ++q) {
            wfr[ks][q] = (short)f2b(p0[q]);
            wfz[ks][q] = (short)f2b(p1[q]);
            wfn[ks][q] = (short)f2b(p2[q]);
        }
    }

    const float* xg = xwt + (size_t)blockIdx.x * (256 * 192 * 16);
    int lo = hi * 4 + jg * 2;            // first of this lane's 2 rows

    float hrA = 0.f, hrB = 0.f;          // h state, exclusive per lane (2 rows)

    int woA = (lo + 0) * 64 + ((((c >> 3) ^ ((lo + 0) & 7))) << 3) + (c & 7);
    int woB = (lo + 1) * 64 + ((((c >> 3) ^ ((lo + 1) & 7))) << 3) + (c & 7);
    int soA = (lo + 0) * 64 + c;         // hstage offsets (linear)
    int soB = (lo + 1) * 64 + c;

    // depth-4 prefetch buffers (static-indexed via full unroll below)
    float2 pxr[4], pxz[4], pxn[4];
#pragma unroll
    for (int u = 0; u < 4; ++u) {
        pxr[u] = *(const float2*)&xg[((size_t)u * 192 + c) * 16 + lo];
        pxz[u] = *(const float2*)&xg[((size_t)u * 192 + 64 + c) * 16 + lo];
        pxn[u] = *(const float2*)&xg[((size_t)u * 192 + 128 + c) * 16 + lo];
    }
    __syncthreads();   // hb[0] visible

    int cur = 0;
    auto step = [&](float2 xr2, float2 xz2, float2 xn2, int ts) {
        f32x4 ar = {br_, br_, br_, br_};
        f32x4 az = {bz_, bz_, bz_, bz_};
        f32x4 an = {bn_, bn_, bn_, bn_};
#pragma unroll
        for (int ks = 0; ks < 2; ++ks) {
            int soff = (((ks << 2) + hi) ^ (fr & 7)) << 3;
            short8 af = *(const short8*)&hb[cur][fr * 64 + soff];
            ar = __builtin_amdgcn_mfma_f32_16x16x32_bf16(af, wfr[ks], ar, 0, 0, 0);
            az = __builtin_amdgcn_mfma_f32_16x16x32_bf16(af, wfz[ks], az, 0, 0, 0);
            an = __builtin_amdgcn_mfma_f32_16x16x32_bf16(af, wfn[ks], an, 0, 0, 0);
        }
        float aR0, aR1, aZ0, aZ1, aN0, aN1;
        if (jg == 0) { aR0 = ar[0]; aR1 = ar[1]; aZ0 = az[0]; aZ1 = az[1]; aN0 = an[0]; aN1 = an[1]; }
        else         { aR0 = ar[2]; aR1 = ar[3]; aZ0 = az[2]; aZ1 = az[3]; aN0 = an[2]; aN1 = an[3]; }
        hrA = gru_gate(xr2.x, xz2.x, xn2.x, aR0, aZ0, aN0, hrA);
        hrB = gru_gate(xr2.y, xz2.y, xn2.y, aR1, aZ1, aN1, hrB);
        u16 v0 = f2b(hrA), v1 = f2b(hrB);
        int nxt = cur ^ 1;
        hb[nxt][woA] = v0; hb[nxt][woB] = v1;       // disjoint rows across wave-pairs
        hstage[ts][soA] = v0; hstage[ts][soB] = v1; // LDS staging (no global store in loop)
        // LDS-only drain + raw barrier: global prefetch loads stay in flight
        asm volatile("s_waitcnt lgkmcnt(0)\n\ts_barrier" ::: "memory");
        cur = nxt;
    };

    for (int t = 0; t < SS; t += 8) {
#pragma unroll
        for (int u = 0; u < 8; ++u) {               // full unroll -> static pxr indices
            int tp = t + u + 4; tp = (tp < SS) ? tp : (SS - 1);
            float2 nr = *(const float2*)&xg[((size_t)tp * 192 + c) * 16 + lo];
            float2 nz = *(const float2*)&xg[((size_t)tp * 192 + 64 + c) * 16 + lo];
            float2 nn = *(const float2*)&xg[((size_t)tp * 192 + 128 + c) * 16 + lo];
            step(pxr[u & 3], pxz[u & 3], pxn[u & 3], u);
            pxr[u & 3] = nr; pxz[u & 3] = nz; pxn[u & 3] = nn;
        }
        // flush 8 steps of hstage -> hsb (coalesced: 8 lanes x 16B = 128B lines)
#pragma unroll
        for (int f = 0; f < 2; ++f) {
            int idx = tid + f * 512;
            int c8 = idx & 7, pair = idx >> 3;      // pair 0..127
            int ts = pair >> 4, row = pair & 15;
            short8 v = *(const short8*)&hstage[ts][row * 64 + c8 * 8];
            *(short8*)&hsb[((size_t)(b0 + row) * SS + t + ts) * 64 + c8 * 8] = v;
        }
        // flush reads must complete before next group's hstage writes
        asm volatile("s_waitcnt lgkmcnt(0)\n\ts_barrier" ::: "memory");
    }
}

// ---------------------------------------------------------------- bf16 MFMA GEMM (BK=64, swizzled)
__device__ __forceinline__ void gl_lds16(const void* g, void* s) {
    __builtin_amdgcn_global_load_lds(
        (const __attribute__((address_space(1))) void*)g,
        (__attribute__((address_space(3))) void*)s, 16, 0, 0);
}

template <int MODE, bool RELU>
__global__ __launch_bounds__(256, 2) void mfma_gemm(const u16* __restrict__ A,
                                                    const u16* __restrict__ W,
                                                    const float* __restrict__ bias,
                                                    float* __restrict__ C,
                                                    u16* __restrict__ Cb,
                                                    const float* __restrict__ lns,
                                                    const float* __restrict__ lnb,
                                                    int M, int N, int K) {
    __shared__ __align__(16) u16 Al[128 * 64];
    __shared__ __align__(16) u16 Bl[128 * 64];
    __shared__ float lred[2][2][128];
    int bm = blockIdx.x, bn = blockIdx.y;
    int tid = threadIdx.x;
    int w = tid >> 6, lane = tid & 63;
    int wrow = (w >> 1) * 64, wcol = (w & 1) * 64;
    int fr = lane & 15, hi = lane >> 4;
    int rl = lane >> 3;
    int sl = lane & 7;
    int ssl = sl ^ rl;

    const u16* Ag = A + ((size_t)bm * 128) * K + ssl * 8;
    const u16* Wg = W + ((size_t)bn * 128) * K + ssl * 8;

    f32x4 acc[4][4];
#pragma unroll
    for (int i = 0; i < 4; ++i)
#pragma unroll
        for (int jj = 0; jj < 4; ++jj) acc[i][jj] = (f32x4){0.f, 0.f, 0.f, 0.f};

    int ar[4], br[4];
#pragma unroll
    for (int m = 0; m < 4; ++m) {
        ar[m] = (wrow + m * 16 + fr) * 64;
        br[m] = (wcol + m * 16 + fr) * 64;
    }
    int swz = (fr & 7);

    for (int kt = 0; kt < K; kt += 64) {
        __syncthreads();
#pragma unroll
        for (int i = 0; i < 4; ++i) {
            int c = w * 4 + i;
            int row = c * 8 + rl;
            gl_lds16(Ag + (size_t)row * K + kt, &Al[c * 512]);
            gl_lds16(Wg + (size_t)row * K + kt, &Bl[c * 512]);
        }
        __syncthreads();
#pragma unroll
        for (int kk = 0; kk < 2; ++kk) {
            short8 a[4], bq[4];
            int soff = (((kk << 2) + hi) ^ swz) << 3;
#pragma unroll
            for (int m = 0; m < 4; ++m)
                a[m] = *(const short8*)&Al[ar[m] + soff];
#pragma unroll
            for (int n = 0; n < 4; ++n)
                bq[n] = *(const short8*)&Bl[br[n] + soff];
#pragma unroll
            for (int m = 0; m < 4; ++m)
#pragma unroll
                for (int n = 0; n < 4; ++n)
                    acc[m][n] = __builtin_amdgcn_mfma_f32_16x16x32_bf16(a[m], bq[n], acc[m][n], 0, 0, 0);
        }
    }

    float bv[4];
#pragma unroll
    for (int n = 0; n < 4; ++n) bv[n] = bias[bn * 128 + wcol + n * 16 + fr];

    if (MODE == 4) {
        float v[4][4][4];
#pragma unroll
        for (int m = 0; m < 4; ++m)
#pragma unroll
            for (int j = 0; j < 4; ++j) {
                int row = bm * 128 + wrow + m * 16 + hi * 4 + j;
#pragma unroll
                for (int n = 0; n < 4; ++n)
                    v[m][n][j] = acc[m][n][j] + bv[n] + C[(size_t)row * 128 + wcol + n * 16 + fr];
            }
#pragma unroll
        for (int m = 0; m < 4; ++m)
#pragma unroll
            for (int j = 0; j < 4; ++j) {
                float s = v[m][0][j] + v[m][1][j] + v[m][2][j] + v[m][3][j];
                float q = v[m][0][j]*v[m][0][j] + v[m][1][j]*v[m][1][j]
                        + v[m][2][j]*v[m][2][j] + v[m][3][j]*v[m][3][j];
#pragma unroll
                for (int off = 1; off <= 8; off <<= 1) {
                    s += __shfl_xor(s, off);
                    q += __shfl_xor(q, off);
                }
                if (fr == 0) {
                    int lrow = wrow + m * 16 + hi * 4 + j;
                    lred[0][w & 1][lrow] = s;
                    lred[1][w & 1][lrow] = q;
                }
            }
        __syncthreads();
        float sv[4], bb[4];
#pragma unroll
        for (int n = 0; n < 4; ++n) {
            sv[n] = lns[wcol + n * 16 + fr];
            bb[n] = lnb[wcol + n * 16 + fr];
        }
#pragma unroll
        for (int m = 0; m < 4; ++m)
#pragma unroll
            for (int j = 0; j < 4; ++j) {
                int lrow = wrow + m * 16 + hi * 4 + j;
                float mean = (lred[0][0][lrow] + lred[0][1][lrow]) * (1.f / 128.f);
                float msq  = (lred[1][0][lrow] + lred[1][1][lrow]) * (1.f / 128.f);
                float rstd = rsqrtf(msq - mean * mean + 1e-5f);
                int row = bm * 128 + lrow;
#pragma unroll
                for (int n = 0; n < 4; ++n) {
                    int col = wcol + n * 16 + fr;
                    float o = (v[m][n][j] - mean) * rstd * sv[n] + bb[n];
                    C[(size_t)row * 128 + col] = o;
                    Cb[(size_t)row * 128 + col] = f2b(o);
                }
            }
    } else {
#pragma unroll
        for (int m = 0; m < 4; ++m) {
#pragma unroll
            for (int j = 0; j < 4; ++j) {
                int row = bm * 128 + wrow + m * 16 + hi * 4 + j;
#pragma unroll
                for (int n = 0; n < 4; ++n) {
                    int col = bn * 128 + wcol + n * 16 + fr;
                    float vv = acc[m][n][j] + bv[n];
                    if (RELU) vv = fmaxf(vv, 0.f);
                    if (MODE & 1) C[(size_t)row * N + col] = vv;
                    if (MODE & 2) Cb[(size_t)row * N + col] = f2b(vv);
                }
            }
        }
    }
}

// ---------------------------------------------------------------- fused FF (unchanged)
__global__ __launch_bounds__(256, 1) void ff_fused_kernel(const u16* __restrict__ zbin,
                                                          const u16* __restrict__ w1,
                                                          const float* __restrict__ b1,
                                                          const u16* __restrict__ w2,
                                                          const float* __restrict__ b2,
                                                          const float* __restrict__ lns,
                                                          const float* __restrict__ lnb,
                                                          float* __restrict__ z,
                                                          u16* __restrict__ zbout) {
    __shared__ __align__(16) u16 ZB[2][128 * 64];
    __shared__ __align__(16) u16 W1C[2][128 * 64];
    __shared__ __align__(16) u16 W2C[2][128 * 64];
    __shared__ __align__(16) u16 A1[2][128 * 64];
    __shared__ float lred[2][2][128];
    int bm = blockIdx.x;
    int tid = threadIdx.x;
    int w = tid >> 6, lane = tid & 63;
    int wrow = (w >> 1) * 64, wcol = (w & 1) * 64;
    int fr = lane & 15, hi = lane >> 4;
    int rl = lane >> 3, ssl = (lane & 7) ^ rl;
    int swz = fr & 7;
    int xh = wrow >> 6;

#pragma unroll
    for (int hk = 0; hk < 2; ++hk)
#pragma unroll
        for (int i = 0; i < 4; ++i) {
            int ch = w * 4 + i, row = ch * 8 + rl;
            gl_lds16(zbin + ((size_t)(bm * 128 + row)) * 128 + hk * 64 + ssl * 8, &ZB[hk][ch * 512]);
        }

    f32x4 acc2[4][4];
#pragma unroll
    for (int m = 0; m < 4; ++m)
#pragma unroll
        for (int n = 0; n < 4; ++n) acc2[m][n] = (f32x4){0.f, 0.f, 0.f, 0.f};

    for (int ci = 0; ci < 16; ++ci) {
#pragma unroll
        for (int hk = 0; hk < 2; ++hk)
#pragma unroll
            for (int i = 0; i < 4; ++i) {
                int ch = w * 4 + i, row = ch * 8 + rl;
                gl_lds16(w1 + ((size_t)(ci * 128 + row)) * 128 + hk * 64 + ssl * 8, &W1C[hk][ch * 512]);
                gl_lds16(w2 + ((size_t)row) * 2048 + ci * 128 + hk * 64 + ssl * 8, &W2C[hk][ch * 512]);
            }
        __syncthreads();

        f32x4 acc1[4][4];
#pragma unroll
        for (int m = 0; m < 4; ++m)
#pragma unroll
            for (int n = 0; n < 4; ++n) acc1[m][n] = (f32x4){0.f, 0.f, 0.f, 0.f};
#pragma unroll
        for (int ks = 0; ks < 4; ++ks) {
            int hk = ks >> 1;
            int soff = ((((ks & 1) << 2) + hi) ^ swz) << 3;
            short8 a[4], b[4];
#pragma unroll
            for (int m = 0; m < 4; ++m)
                a[m] = *(const short8*)&W1C[hk][(wrow + m * 16 + fr) * 64 + soff];
#pragma unroll
            for (int n = 0; n < 4; ++n)
                b[n] = *(const short8*)&ZB[hk][(wcol + n * 16 + fr) * 64 + soff];
#pragma unroll
            for (int m = 0; m < 4; ++m)
#pragma unroll
                for (int n = 0; n < 4; ++n)
                    acc1[m][n] = __builtin_amdgcn_mfma_f32_16x16x32_bf16(a[m], b[n], acc1[m][n], 0, 0, 0);
        }
#pragma unroll
        for (int m = 0; m < 4; ++m) {
            int x0 = wrow + m * 16 + hi * 4;
            float4 bb = *(const float4*)&b1[ci * 128 + x0];
            int slot = (x0 & 63) >> 3;
            int wadd = x0 & 7;
#pragma unroll
            for (int n = 0; n < 4; ++n) {
                int r = wcol + n * 16 + fr;
                float v0 = fmaxf(acc1[m][n][0] + bb.x, 0.f);
                float v1 = fmaxf(acc1[m][n][1] + bb.y, 0.f);
                float v2 = fmaxf(acc1[m][n][2] + bb.z, 0.f);
                float v3 = fmaxf(acc1[m][n][3] + bb.w, 0.f);
                uint2 pk;
                pk.x = (unsigned)f2b(v0) | ((unsigned)f2b(v1) << 16);
                pk.y = (unsigned)f2b(v2) | ((unsigned)f2b(v3) << 16);
                *(uint2*)&A1[xh][r * 64 + ((slot ^ (r & 7)) << 3) + wadd] = pk;
            }
        }
        __syncthreads();

#pragma unroll
        for (int ks = 0; ks < 4; ++ks) {
            int hk = ks >> 1;
            int soff = ((((ks & 1) << 2) + hi) ^ swz) << 3;
            short8 a[4], b[4];
#pragma unroll
            for (int m = 0; m < 4; ++m)
                a[m] = *(const short8*)&W2C[hk][(wrow + m * 16 + fr) * 64 + soff];
#pragma unroll
            for (int n = 0; n < 4; ++n)
                b[n] = *(const short8*)&A1[hk][(wcol + n * 16 + fr) * 64 + soff];
#pragma unroll
            for (int m = 0; m < 4; ++m)
#pragma unroll
                for (int n = 0; n < 4; ++n)
                    acc2[m][n] = __builtin_amdgcn_mfma_f32_16x16x32_bf16(a[m], b[n], acc2[m][n], 0, 0, 0);
        }
        __syncthreads();
    }

    float vv[4][4][4];
#pragma unroll
    for (int m = 0; m < 4; ++m) {
        int x0 = wrow + m * 16 + hi * 4;
        float4 bb = *(const float4*)&b2[x0];
#pragma unroll
        for (int n = 0; n < 4; ++n) {
            int y = wcol + n * 16 + fr;
            float4 zo = *(const float4*)&z[((size_t)(bm * 128 + y)) * 128 + x0];
            vv[m][n][0] = acc2[m][n][0] + bb.x + zo.x;
            vv[m][n][1] = acc2[m][n][1] + bb.y + zo.y;
            vv[m][n][2] = acc2[m][n][2] + bb.z + zo.z;
            vv[m][n][3] = acc2[m][n][3] + bb.w + zo.w;
        }
    }
#pragma unroll
    for (int n = 0; n < 4; ++n) {
        float s = 0.f, q = 0.f;
#pragma unroll
        for (int m = 0; m < 4; ++m)
#pragma unroll
            for (int j = 0; j < 4; ++j) { float v = vv[m][n][j]; s += v; q += v * v; }
        s += __shfl_xor(s, 16); s += __shfl_xor(s, 32);
        q += __shfl_xor(q, 16); q += __shfl_xor(q, 32);
        if (hi == 0) {
            int y = wcol + n * 16 + fr;
            lred[0][xh][y] = s;
            lred[1][xh][y] = q;
        }
    }
    __syncthreads();
#pragma unroll
    for (int n = 0; n < 4; ++n) {
        int y = wcol + n * 16 + fr;
        float mean = (lred[0][0][y] + lred[0][1][y]) * (1.f / 128.f);
        float msq  = (lred[1][0][y] + lred[1][1][y]) * (1.f / 128.f);
        float rstd = rsqrtf(msq - mean * mean + 1e-5f);
#pragma unroll
        for (int m = 0; m < 4; ++m) {
            int x0 = wrow + m * 16 + hi * 4;
            float4 sv = *(const float4*)&lns[x0];
            float4 bv = *(const float4*)&lnb[x0];
            float o0 = (vv[m][n][0] - mean) * rstd * sv.x + bv.x;
            float o1 = (vv[m][n][1] - mean) * rstd * sv.y + bv.y;
            float o2 = (vv[m][n][2] - mean) * rstd * sv.z + bv.z;
            float o3 = (vv[m][n][3] - mean) * rstd * sv.w + bv.w;
            size_t zoff = ((size_t)(bm * 128 + y)) * 128 + x0;
            *(float4*)&z[zoff] = (float4){o0, o1, o2, o3};
            uint2 pk;
            pk.x = (unsigned)f2b(o0) | ((unsigned)f2b(o1) << 16);
            pk.y = (unsigned)f2b(o2) | ((unsigned)f2b(o3) << 16);
            *(uint2*)&zbout[zoff] = pk;
        }
    }
}

// ---------------------------------------------------------------- MFMA attention (unchanged)
__global__ __launch_bounds__(256) void attn_mfma_kernel(const u16* __restrict__ qkv,
                                                        const float* __restrict__ tm,
                                                        u16* __restrict__ attno) {
    __shared__ __align__(16) u16 Kl[256 * 40];
    __shared__ __align__(16) u16 Vt[32 * 264];
    __shared__ __align__(16) u16 Pl[4][64 * 72];
    __shared__ float tmb[256];
    int bh = blockIdx.x;
    int b = bh >> 2, hd = bh & 3;
    int tid = threadIdx.x;
    int w = tid >> 6, lane = tid & 63;
    int fr = lane & 15, hi = lane >> 4;
    const u16* base = qkv + (size_t)b * SS * 384 + hd * 32;

    for (int idx = tid; idx < 1024; idx += 256) {
        int r = idx >> 2, s = idx & 3;
        short8 v = *(const short8*)(base + (size_t)r * 384 + 128 + s * 8);
        *(short8*)&Kl[r * 40 + s * 8] = v;
    }
    for (int idx = tid; idx < 1024; idx += 256) {
        int r = idx >> 2, s = idx & 3;
        short8 v = *(const short8*)(base + (size_t)r * 384 + 256 + s * 8);
#pragma unroll
        for (int q = 0; q < 8; ++q) Vt[(s * 8 + q) * 264 + r] = (u16)v[q];
    }
    tmb[tid] = (tm[b * SS + tid] > 0.f) ? 0.f : NEGV;

    int q0 = w * 64;
    short8 qf[4];
#pragma unroll
    for (int m = 0; m < 4; ++m)
        qf[m] = *(const short8*)(base + (size_t)(q0 + m * 16 + fr) * 384 + hi * 8);
    __syncthreads();

    const float scale = 0.17677669529663687f;
    f32x4 accO[4][2];
#pragma unroll
    for (int m = 0; m < 4; ++m) {
        accO[m][0] = (f32x4){0.f, 0.f, 0.f, 0.f};
        accO[m][1] = (f32x4){0.f, 0.f, 0.f, 0.f};
    }
    float den[4][4];
#pragma unroll
    for (int m = 0; m < 4; ++m)
#pragma unroll
        for (int j = 0; j < 4; ++j) den[m][j] = 0.f;

    u16* pw = &Pl[w][0];

    for (int kt = 0; kt < 4; ++kt) {
        f32x4 accS[4][4];
#pragma unroll
        for (int m = 0; m < 4; ++m)
#pragma unroll
            for (int n = 0; n < 4; ++n) accS[m][n] = (f32x4){0.f, 0.f, 0.f, 0.f};
        short8 kf[4];
#pragma unroll
        for (int n = 0; n < 4; ++n)
            kf[n] = *(const short8*)&Kl[(kt * 64 + n * 16 + fr) * 40 + hi * 8];
#pragma unroll
        for (int m = 0; m < 4; ++m)
#pragma unroll
            for (int n = 0; n < 4; ++n)
                accS[m][n] = __builtin_amdgcn_mfma_f32_16x16x32_bf16(qf[m], kf[n], accS[m][n], 0, 0, 0);

        float bias[4];
#pragma unroll
        for (int n = 0; n < 4; ++n) bias[n] = tmb[kt * 64 + n * 16 + fr];

#pragma unroll
        for (int m = 0; m < 4; ++m) {
            float rs0 = 0.f, rs1 = 0.f, rs2 = 0.f, rs3 = 0.f;
#pragma unroll
            for (int n = 0; n < 4; ++n) {
                float p0 = __expf(accS[m][n][0] * scale + bias[n]);
                float p1 = __expf(accS[m][n][1] * scale + bias[n]);
                float p2 = __expf(accS[m][n][2] * scale + bias[n]);
                float p3 = __expf(accS[m][n][3] * scale + bias[n]);
                rs0 += p0; rs1 += p1; rs2 += p2; rs3 += p3;
                int cb = n * 16 + fr;
                pw[(m * 16 + hi * 4 + 0) * 72 + cb] = f2b(p0);
                pw[(m * 16 + hi * 4 + 1) * 72 + cb] = f2b(p1);
                pw[(m * 16 + hi * 4 + 2) * 72 + cb] = f2b(p2);
                pw[(m * 16 + hi * 4 + 3) * 72 + cb] = f2b(p3);
            }
#pragma unroll
            for (int off = 1; off <= 8; off <<= 1) {
                rs0 += __shfl_xor(rs0, off);
                rs1 += __shfl_xor(rs1, off);
                rs2 += __shfl_xor(rs2, off);
                rs3 += __shfl_xor(rs3, off);
            }
            den[m][0] += rs0; den[m][1] += rs1; den[m][2] += rs2; den[m][3] += rs3;
        }
        asm volatile("s_waitcnt lgkmcnt(0)" ::: "memory");

#pragma unroll
        for (int ks = 0; ks < 2; ++ks) {
            short8 pf[4], vf[2];
#pragma unroll
            for (int m = 0; m < 4; ++m)
                pf[m] = *(const short8*)&pw[(m * 16 + fr) * 72 + ks * 32 + hi * 8];
#pragma unroll
            for (int nd = 0; nd < 2; ++nd)
                vf[nd] = *(const short8*)&Vt[(nd * 16 + fr) * 264 + kt * 64 + ks * 32 + hi * 8];
#pragma unroll
            for (int m = 0; m < 4; ++m)
#pragma unroll
                for (int nd = 0; nd < 2; ++nd)
                    accO[m][nd] = __builtin_amdgcn_mfma_f32_16x16x32_bf16(pf[m], vf[nd], accO[m][nd], 0, 0, 0);
        }
    }

    u16* orow = attno + (size_t)(b * SS + q0) * DD + hd * 32;
#pragma unroll
    for (int m = 0; m < 4; ++m)
#pragma unroll
        for (int j = 0; j < 4; ++j) {
            float inv = 1.f / den[m][j];
            int qr = m * 16 + hi * 4 + j;
            orow[(size_t)qr * DD + fr]      = f2b(accO[m][0][j] * inv);
            orow[(size_t)qr * DD + 16 + fr] = f2b(accO[m][1][j] * inv);
        }
}

// ---------------------------------------------------------------- fused score + softmax-pool + routed heads
__global__ __launch_bounds__(256) void pool_all_kernel(const float* __restrict__ z,
                                                       const float* __restrict__ score_w,
                                                       const float* __restrict__ score_b,
                                                       const float* __restrict__ tm,
                                                       const float* __restrict__ reg_w,
                                                       const float* __restrict__ reg_b,
                                                       const float* __restrict__ bin_w,
                                                       const float* __restrict__ bin_b,
                                                       const int* __restrict__ wid,
                                                       float* __restrict__ out) {
    int b = blockIdx.x;
    int tid = threadIdx.x;
    __shared__ float sw[128];
    __shared__ float al[SS];
    __shared__ float red[8];
    __shared__ float pp[2][128];
    __shared__ float p[128];

    if (tid < 128) sw[tid] = score_w[tid];
    __syncthreads();

    const float* zr = z + ((size_t)b * SS + tid) * DD;
    float acc = 0.f;
#pragma unroll
    for (int j = 0; j < 128; j += 4) {
        float4 a = *(const float4*)&zr[j];
        float4 wv = *(const float4*)&sw[j];
        acc += a.x * wv.x + a.y * wv.y + a.z * wv.z + a.w * wv.w;
    }
    float sc = acc + score_b[0];
    sc = (tm[b * SS + tid] > 0.f) ? sc : NEGV;

    float m = sc;
#pragma unroll
    for (int off = 32; off; off >>= 1) m = fmaxf(m, __shfl_xor(m, off));
    if ((tid & 63) == 0) red[tid >> 6] = m;
    __syncthreads();
    m = fmaxf(fmaxf(red[0], red[1]), fmaxf(red[2], red[3]));
    float e = __expf(sc - m);
    float ssum = e;
#pragma unroll
    for (int off = 32; off; off >>= 1) ssum += __shfl_xor(ssum, off);
    if ((tid & 63) == 0) red[4 + (tid >> 6)] = ssum;
    __syncthreads();
    ssum = red[4] + red[5] + red[6] + red[7];
    al[tid] = e / ssum;
    __syncthreads();

    int d = tid & 127, half = tid >> 7;
    float pa = 0.f;
    for (int t = half; t < SS; t += 2) pa += al[t] * z[((size_t)b * SS + t) * DD + d];
    pp[half][d] = pa;
    __syncthreads();
    if (tid < 128) p[tid] = pp[0][tid] + pp[1][tid];
    __syncthreads();

    if (tid < 9) {
        int wi = wid[b];
        const float* wrow;
        float bias;
        if (tid < 8) { wrow = reg_w + ((size_t)wi * 8 + tid) * 128; bias = reg_b[wi * 8 + tid]; }
        else         { wrow = bin_w + (size_t)wi * 128;             bias = bin_b[wi]; }
        float hacc = bias;
        for (int k = 0; k < 128; ++k) hacc += wrow[k] * p[k];
        if (tid < 8) out[b * 8 + tid] = hacc;
        else         out[1024 + b] = hacc;
    }
}

// ================================================================ host
extern "C" void kernel_launch(void* const* d_in, const int* in_sizes, int n_in,
                              void* d_out, int out_size, void* d_ws, size_t ws_size,
                              hipStream_t stream) {
    const float* x         = (const float*)d_in[0];
    const float* mask      = (const float*)d_in[1];
    const float* delta     = (const float*)d_in[2];
    const float* gru_w_ih  = (const float*)d_in[3];
    const float* gru_w_hh  = (const float*)d_in[4];
    const float* gru_b_ih  = (const float*)d_in[5];
    const float* gru_b_hh  = (const float*)d_in[6];
    const float* dm_w      = (const float*)d_in[7];
    const float* dm_b      = (const float*)d_in[8];
    const float* in_proj_w = (const float*)d_in[9];
    const float* in_proj_b = (const float*)d_in[10];
    const float* out_proj_w= (const float*)d_in[11];
    const float* out_proj_b= (const float*)d_in[12];
    const float* lin1_w    = (const float*)d_in[13];
    const float* lin1_b    = (const float*)d_in[14];
    const float* lin2_w    = (const float*)d_in[15];
    const float* lin2_b    = (const float*)d_in[16];
    const float* ln1_s     = (const float*)d_in[17];
    const float* ln1_bb    = (const float*)d_in[18];
    const float* ln2_s     = (const float*)d_in[19];
    const float* ln2_bb    = (const float*)d_in[20];
    const float* score_w   = (const float*)d_in[21];
    const float* score_b   = (const float*)d_in[22];
    const float* reg_w     = (const float*)d_in[23];
    const float* reg_b     = (const float*)d_in[24];
    const float* bin_w     = (const float*)d_in[25];
    const float* bin_b     = (const float*)d_in[26];
    const int*   window_id = (const int*)d_in[27];
    float* out = (float*)d_out;

    char* w8 = (char*)d_ws;
    float* z      = (float*)(w8 + 0);            // 16,777,216
    u16*   zb     = (u16*)  (w8 + 16777216);     //  8,388,608
    u16*   hsb    = (u16*)  (w8 + 25165824);     //  4,194,304
    u16*   wb_dm  = (u16*)  (w8 + 29360128);     //     16,384
    u16*   wb_ip  = (u16*)  (w8 + 29376512);     //    196,608
    u16*   wb_op  = (u16*)  (w8 + 29573120);     //     65,536
    u16*   wb_l1  = (u16*)  (w8 + 29638656);     //  1,048,576
    u16*   wb_l2  = (u16*)  (w8 + 30687232);     //  1,048,576
    float* tm     = (float*)(w8 + 31735808);     //    131,072
    float* xwt    = (float*)(w8 + 32063488);     // 25,165,824 (GRU: xwt fp32 | later: qkvb bf16)
    u16*   qkvb   = (u16*)  (w8 + 32063488);
    u16*   attnob = (u16*)  (w8 + 57229312);     //  8,388,608   (total ~65.6MB)

    cvt_all_kernel<<<580, 256, 0, stream>>>(dm_w, in_proj_w, out_proj_w, lin1_w, lin2_w,
                                            wb_dm, wb_ip, wb_op, wb_l1, wb_l2);

    tm_kernel<<<(BB * SS + 255) / 256, 256, 0, stream>>>(mask, tm);
    xw_kernel<<<2048, 192, 0, stream>>>(x, mask, delta, gru_w_ih, gru_b_ih, xwt);
    gru_scan_kernel<<<8, 512, 0, stream>>>(gru_w_hh, gru_b_hh, xwt, hsb);

    mfma_gemm<3, false><<<dim3(256, 1), 256, 0, stream>>>(
        hsb, wb_dm, dm_b, z, zb, nullptr, nullptr, 32768, 128, 64);

    for (int l = 0; l < LL; ++l) {
        mfma_gemm<2, false><<<dim3(256, 3), 256, 0, stream>>>(
            zb, wb_ip + (size_t)l * 49152, in_proj_b + l * 384, nullptr, qkvb,
            nullptr, nullptr, 32768, 384, 128);
        attn_mfma_kernel<<<BB * NHH, 256, 0, stream>>>(qkvb, tm, attnob);
        mfma_gemm<4, false><<<dim3(256, 1), 256, 0, stream>>>(
            attnob, wb_op + (size_t)l * 16384, out_proj_b + l * 128, z, zb,
            ln1_s + l * 128, ln1_bb + l * 128, 32768, 128, 128);
        ff_fused_kernel<<<256, 256, 0, stream>>>(
            zb, wb_l1 + (size_t)l * 262144, lin1_b + l * 2048,
            wb_l2 + (size_t)l * 262144, lin2_b + l * 128,
            ln2_s + l * 128, ln2_bb + l * 128, z, zb);
    }

    pool_all_kernel<<<BB, 256, 0, stream>>>(z, score_w, score_b, tm,
                                            reg_w, reg_b, bin_w, bin_b, window_id, out);
}